// Round 1
// baseline (1067.130 us; speedup 1.0000x reference)
//
#include <hip/hip_runtime.h>
#include <hip/hip_bf16.h>
#include <stdint.h>

#define TSEQ   2048
#define DMODEL 6144
#define NHEADS 48
#define NKVH   8
#define HDIM   128
#define QKVC   8192   // (48 + 2*8) * 128
#define GRP    6      // NHEADS / NKVH

typedef __attribute__((ext_vector_type(8))) short short8;
typedef __attribute__((ext_vector_type(4))) float f32x4;

// ---------- helpers ----------

__device__ __forceinline__ unsigned short f2b(float f) {
  union { float f; unsigned int u; } v; v.f = f;
  unsigned int u = v.u;
  unsigned int r = (u + 0x7FFFu + ((u >> 16) & 1u)) >> 16;  // RNE
  return (unsigned short)r;
}

#if __has_builtin(__builtin_amdgcn_exp2f)
#define EXP2(x) __builtin_amdgcn_exp2f(x)
#else
#define EXP2(x) exp2f(x)
#endif
#if __has_builtin(__builtin_amdgcn_rcpf)
#define RCP(x) __builtin_amdgcn_rcpf(x)
#else
#define RCP(x) (1.0f / (x))
#endif

typedef const __attribute__((address_space(1))) void* as1_cvp;
typedef __attribute__((address_space(3))) void* as3_vp;

__device__ __forceinline__ void gload_lds16(const void* g, void* l) {
  // LDS dest must be wave-uniform base + lane*16 (layout below is linear in tid)
  __builtin_amdgcn_global_load_lds(
      (as1_cvp)(uintptr_t)g,
      (as3_vp)(unsigned int)(uintptr_t)l, 16, 0, 0);
}

// ---------- prep kernels ----------

__global__ __launch_bounds__(256) void k_cvt(const float* __restrict__ in,
                                             unsigned short* __restrict__ outp, int n) {
  int i = (blockIdx.x * 256 + threadIdx.x) * 4;
  if (i + 3 < n) {
    float4 v = *(const float4*)(in + i);
    union { unsigned short s[4]; uint2 u; } o;
    o.s[0] = f2b(v.x); o.s[1] = f2b(v.y); o.s[2] = f2b(v.z); o.s[3] = f2b(v.w);
    *(uint2*)(outp + i) = o.u;
  }
}

// in: R x C (f32, row-major) -> out: C x R (bf16)
__global__ __launch_bounds__(256) void k_tr(const float* __restrict__ in,
                                            unsigned short* __restrict__ out, int R, int C) {
  __shared__ unsigned short tile[64][65];
  const int tx = threadIdx.x & 63;
  const int ty = threadIdx.x >> 6;   // 0..3
  const int br = blockIdx.y * 64;
  const int bc = blockIdx.x * 64;
#pragma unroll
  for (int j = 0; j < 16; ++j) {
    int r = ty * 16 + j;
    tile[r][tx] = f2b(in[(size_t)(br + r) * C + bc + tx]);
  }
  __syncthreads();
#pragma unroll
  for (int j = 0; j < 16; ++j) {
    int r = ty * 16 + j;
    out[(size_t)(bc + r) * R + br + tx] = tile[tx][r];
  }
}

__global__ void k_trig(const int* __restrict__ pos, float* __restrict__ cs,
                       float* __restrict__ sn) {
  int t = blockIdx.x, i = threadIdx.x;  // block=64
  float p = (float)pos[t];
  // inv_freq = 10000^(-2i/128) = 2^(-(2i/128)*log2(10000))
  float inv = EXP2(-(float)(2 * i) * (1.0f / 128.0f) * 13.287712379549449f);
  float f = p * inv;
  cs[t * 64 + i] = cosf(f);
  sn[t * 64 + i] = sinf(f);
}

// ---------- GEMM: A[M][K] bf16 row-major, Bt[N][K] bf16 (B transposed), C[M][N] f32 ----------

__global__ __launch_bounds__(256, 2) void k_gemm(const unsigned short* __restrict__ A,
                                                 const unsigned short* __restrict__ Bt,
                                                 float* __restrict__ C,
                                                 int M, int N, int K) {
  __shared__ unsigned short As[128 * 32];
  __shared__ unsigned short Bs[128 * 32];
  const int tid  = threadIdx.x;
  const int lane = tid & 63;
  const int wave = tid >> 6;
  const int m0 = blockIdx.y * 128;
  const int n0 = blockIdx.x * 128;
  const int wr = (wave >> 1) * 64;
  const int wc = (wave & 1) * 64;
  const int lr  = lane & 15;
  const int lk  = (lane >> 4) * 8;
  const int li4 = (lane >> 4) * 4;

  f32x4 acc[4][4];
#pragma unroll
  for (int m = 0; m < 4; ++m)
#pragma unroll
    for (int n = 0; n < 4; ++n) acc[m][n] = (f32x4){0.f, 0.f, 0.f, 0.f};

  const int fl0 = tid * 8;            // element offset of this thread's 16B chunk
  const int r0 = fl0 >> 5, c0 = fl0 & 31;
  const int fl1 = (256 + tid) * 8;
  const int r1 = fl1 >> 5, c1 = fl1 & 31;
  const unsigned short* Ag0 = A  + (size_t)(m0 + r0) * K + c0;
  const unsigned short* Ag1 = A  + (size_t)(m0 + r1) * K + c1;
  const unsigned short* Bg0 = Bt + (size_t)(n0 + r0) * K + c0;
  const unsigned short* Bg1 = Bt + (size_t)(n0 + r1) * K + c1;

  for (int k0 = 0; k0 < K; k0 += 32) {
    gload_lds16(Ag0 + k0, &As[fl0]);
    gload_lds16(Ag1 + k0, &As[fl1]);
    gload_lds16(Bg0 + k0, &Bs[fl0]);
    gload_lds16(Bg1 + k0, &Bs[fl1]);
    __syncthreads();   // drains vmcnt before barrier (compiler-emitted)
    short8 af[4], bf[4];
#pragma unroll
    for (int m = 0; m < 4; ++m) af[m] = *(const short8*)&As[(wr + m * 16 + lr) * 32 + lk];
#pragma unroll
    for (int n = 0; n < 4; ++n) bf[n] = *(const short8*)&Bs[(wc + n * 16 + lr) * 32 + lk];
#pragma unroll
    for (int m = 0; m < 4; ++m)
#pragma unroll
      for (int n = 0; n < 4; ++n)
        acc[m][n] = __builtin_amdgcn_mfma_f32_16x16x32_bf16(af[m], bf[n], acc[m][n], 0, 0, 0);
    __syncthreads();
  }

#pragma unroll
  for (int m = 0; m < 4; ++m)
#pragma unroll
    for (int n = 0; n < 4; ++n)
#pragma unroll
      for (int i = 0; i < 4; ++i) {
        int row = m0 + wr + m * 16 + li4 + i;
        int col = n0 + wc + n * 16 + lr;
        C[(size_t)row * N + col] = acc[m][n][i];
      }
}

// ---------- RoPE + split: QKV f32 [T][8192] -> Q[h][t][d], K[h][t][d], Vt[h][d][t] (bf16) ----------

__global__ __launch_bounds__(256) void k_rope(const float* __restrict__ qkv,
                                              const float* __restrict__ cs,
                                              const float* __restrict__ sn,
                                              unsigned short* __restrict__ Q,
                                              unsigned short* __restrict__ K,
                                              unsigned short* __restrict__ Vt) {
  const int t = blockIdx.x;
  const int tid = threadIdx.x;
  const float* row = qkv + (size_t)t * QKVC;
  const float* c = cs + t * 64;
  const float* s = sn + t * 64;
  // Q: 48 heads * 64 pairs
  for (int p = tid; p < NHEADS * 64; p += 256) {
    int h = p >> 6, i = p & 63;
    float x1 = row[h * 128 + i], x2 = row[h * 128 + 64 + i];
    float cc = c[i], ss = s[i];
    size_t base = ((size_t)h * TSEQ + t) * HDIM;
    Q[base + i]      = f2b(x1 * cc - x2 * ss);
    Q[base + 64 + i] = f2b(x2 * cc + x1 * ss);
  }
  // K: 8 heads * 64 pairs
  for (int p = tid; p < NKVH * 64; p += 256) {
    int h = p >> 6, i = p & 63;
    float x1 = row[DMODEL + h * 128 + i], x2 = row[DMODEL + h * 128 + 64 + i];
    float cc = c[i], ss = s[i];
    size_t base = ((size_t)h * TSEQ + t) * HDIM;
    K[base + i]      = f2b(x1 * cc - x2 * ss);
    K[base + 64 + i] = f2b(x2 * cc + x1 * ss);
  }
  // V transposed: Vt[h][d][t]
  for (int p = tid; p < NKVH * HDIM; p += 256) {
    int h = p >> 7, d = p & 127;
    Vt[((size_t)h * HDIM + d) * TSEQ + t] = f2b(row[DMODEL + NKVH * HDIM + h * 128 + d]);
  }
}

// ---------- attention: per (head, 128-row q tile); 4 independent waves x 32 rows ----------
// P = softmax(cap*tanh(S/cap)) with static max=cap:
//   exp(l - 30) = exp(-60/(exp(s/15)+1)) = 2^(-86.5617 * rcp(2^(s*0.09618)+1))

__global__ __launch_bounds__(256, 2) void k_attn(const unsigned short* __restrict__ Q,
                                                 const unsigned short* __restrict__ K,
                                                 const unsigned short* __restrict__ V,  // Vt[h][d][t]
                                                 unsigned short* __restrict__ O) {
  __shared__ unsigned short P[4][32 * 128];
  const int h = blockIdx.y;
  const int qb = blockIdx.x;
  const int tid = threadIdx.x, wave = tid >> 6, lane = tid & 63;
  const int lr = lane & 15, lk = (lane >> 4) * 8, li4 = (lane >> 4) * 4;
  const unsigned short* Qh = Q + (size_t)h * (TSEQ * HDIM);
  const unsigned short* Kh = K + (size_t)(h / GRP) * (TSEQ * HDIM);
  const unsigned short* Vh = V + (size_t)(h / GRP) * (TSEQ * HDIM);
  const int t0 = qb * 128 + wave * 32;

  short8 qf[2][4];
#pragma unroll
  for (int m = 0; m < 2; ++m)
#pragma unroll
    for (int ks = 0; ks < 4; ++ks)
      qf[m][ks] = *(const short8*)(Qh + (size_t)(t0 + m * 16 + lr) * HDIM + ks * 32 + lk);

  f32x4 oacc[2][8];
#pragma unroll
  for (int m = 0; m < 2; ++m)
#pragma unroll
    for (int n = 0; n < 8; ++n) oacc[m][n] = (f32x4){0.f, 0.f, 0.f, 0.f};
  float rs[2][4] = {{0.f, 0.f, 0.f, 0.f}, {0.f, 0.f, 0.f, 0.f}};
  unsigned short* Pw = P[wave];

  for (int st = 0; st <= qb; ++st) {
    const int s0 = st * 128;
    f32x4 sacc[2][8];
#pragma unroll
    for (int m = 0; m < 2; ++m)
#pragma unroll
      for (int n = 0; n < 8; ++n) sacc[m][n] = (f32x4){0.f, 0.f, 0.f, 0.f};

#pragma unroll
    for (int ks = 0; ks < 4; ++ks) {
      short8 kf[8];
#pragma unroll
      for (int n = 0; n < 8; ++n)
        kf[n] = *(const short8*)(Kh + (size_t)(s0 + n * 16 + lr) * HDIM + ks * 32 + lk);
#pragma unroll
      for (int m = 0; m < 2; ++m)
#pragma unroll
        for (int n = 0; n < 8; ++n)
          sacc[m][n] = __builtin_amdgcn_mfma_f32_16x16x32_bf16(qf[m][ks], kf[n], sacc[m][n], 0, 0, 0);
    }

    const bool diag = (st == qb);
#pragma unroll
    for (int m = 0; m < 2; ++m)
#pragma unroll
      for (int n = 0; n < 8; ++n)
#pragma unroll
        for (int i = 0; i < 4; ++i) {
          float sv = sacc[m][n][i] * 0.08838834764831845f;  // 1/sqrt(128)
          float e = EXP2(sv * 0.09617966939259757f);        // e^(s/15)
          float p = EXP2(-86.5617024533378f * RCP(e + 1.0f));
          if (diag) {
            int scol = s0 + n * 16 + lr;
            int trow = t0 + m * 16 + li4 + i;
            if (scol > trow) p = 0.f;
          }
          rs[m][i] += p;
          Pw[(m * 16 + li4 + i) * 128 + n * 16 + lr] = f2b(p);
        }

    // PV: out += P * V   (A = P rows, B = Vt rows)
#pragma unroll
    for (int ks = 0; ks < 4; ++ks) {
      short8 pf[2], vf[8];
      pf[0] = *(const short8*)&Pw[(0 * 16 + lr) * 128 + ks * 32 + lk];
      pf[1] = *(const short8*)&Pw[(1 * 16 + lr) * 128 + ks * 32 + lk];
#pragma unroll
      for (int n = 0; n < 8; ++n)
        vf[n] = *(const short8*)(Vh + (size_t)(n * 16 + lr) * TSEQ + s0 + ks * 32 + lk);
#pragma unroll
      for (int m = 0; m < 2; ++m)
#pragma unroll
        for (int n = 0; n < 8; ++n)
          oacc[m][n] = __builtin_amdgcn_mfma_f32_16x16x32_bf16(pf[m], vf[n], oacc[m][n], 0, 0, 0);
    }
  }

  // row-sum reduce across the 16-lane col group, then normalize+store
#pragma unroll
  for (int m = 0; m < 2; ++m)
#pragma unroll
    for (int i = 0; i < 4; ++i) {
      float v = rs[m][i];
      v += __shfl_xor(v, 1, 64);
      v += __shfl_xor(v, 2, 64);
      v += __shfl_xor(v, 4, 64);
      v += __shfl_xor(v, 8, 64);
      rs[m][i] = RCP(v);
    }
#pragma unroll
  for (int m = 0; m < 2; ++m)
#pragma unroll
    for (int n = 0; n < 8; ++n)
#pragma unroll
      for (int i = 0; i < 4; ++i) {
        int trow = t0 + m * 16 + li4 + i;
        int d = n * 16 + lr;
        O[(size_t)trow * DMODEL + h * HDIM + d] = f2b(oacc[m][n][i] * rs[m][i]);
      }
}

// ---------- launch ----------

extern "C" void kernel_launch(void* const* d_in, const int* in_sizes, int n_in,
                              void* d_out, int out_size, void* d_ws, size_t ws_size,
                              hipStream_t stream) {
  const int*   pos  = (const int*)d_in[0];
  const float* hid  = (const float*)d_in[1];
  const float* wqkv = (const float*)d_in[2];
  const float* wo   = (const float*)d_in[3];
  float* out = (float*)d_out;
  char* ws = (char*)d_ws;

  // workspace layout (bytes)
  const size_t O_XB   = 0;                         // Xb bf16 [2048][6144]; later attn_out
  const size_t O_WQT  = 25165824;                  // Wqkv^T bf16 [8192][6144]; later Q/K/Vt
  const size_t O_WOT  = 125829120;                 // Wo^T bf16 [6144][6144]
  const size_t O_QKV  = 201326592;                 // QKV f32 [2048][8192]
  const size_t O_TRIG = 268435456;                 // cos/sin f32 [2048][64] each

  unsigned short* Xb  = (unsigned short*)(ws + O_XB);
  unsigned short* Wqt = (unsigned short*)(ws + O_WQT);
  unsigned short* Wot = (unsigned short*)(ws + O_WOT);
  float* QKV = (float*)(ws + O_QKV);
  float* CS  = (float*)(ws + O_TRIG);
  float* SN  = CS + TSEQ * 64;
  unsigned short* Qr = Wqt;                             // [48][2048][128]
  unsigned short* Kr = Wqt + (size_t)NHEADS * TSEQ * HDIM;   // [8][2048][128]
  unsigned short* Vt = Kr + (size_t)NKVH * TSEQ * HDIM;      // [8][128][2048]
  unsigned short* AO = Xb;                              // attn_out bf16 [2048][6144]

  k_cvt<<<(TSEQ * DMODEL) / (256 * 4), 256, 0, stream>>>(hid, Xb, TSEQ * DMODEL);
  k_tr<<<dim3(QKVC / 64, DMODEL / 64), 256, 0, stream>>>(wqkv, Wqt, DMODEL, QKVC);
  k_tr<<<dim3(DMODEL / 64, DMODEL / 64), 256, 0, stream>>>(wo, Wot, DMODEL, DMODEL);
  k_trig<<<TSEQ, 64, 0, stream>>>(pos, CS, SN);

  k_gemm<<<dim3(QKVC / 128, TSEQ / 128), 256, 0, stream>>>(Xb, Wqt, QKV, TSEQ, QKVC, DMODEL);
  k_rope<<<TSEQ, 256, 0, stream>>>(QKV, CS, SN, Qr, Kr, Vt);
  k_attn<<<dim3(TSEQ / 128, NHEADS), 256, 0, stream>>>(Qr, Kr, Vt, AO);
  k_gemm<<<dim3(DMODEL / 128, TSEQ / 128), 256, 0, stream>>>(AO, Wot, out, TSEQ, DMODEL, DMODEL);
}

// Round 2
// 741.621 us; speedup vs baseline: 1.4389x; 1.4389x over previous
//
#include <hip/hip_runtime.h>
#include <hip/hip_bf16.h>
#include <stdint.h>

#define TSEQ   2048
#define DMODEL 6144
#define NHEADS 48
#define NKVH   8
#define HDIM   128
#define QKVC   8192   // (48 + 2*8) * 128
#define GRP    6      // NHEADS / NKVH

typedef __attribute__((ext_vector_type(8))) short short8;
typedef __attribute__((ext_vector_type(4))) float f32x4;

// ---------- helpers ----------

__device__ __forceinline__ unsigned short f2b(float f) {
  union { float f; unsigned int u; } v; v.f = f;
  unsigned int u = v.u;
  unsigned int r = (u + 0x7FFFu + ((u >> 16) & 1u)) >> 16;  // RNE
  return (unsigned short)r;
}

#if __has_builtin(__builtin_amdgcn_exp2f)
#define EXP2(x) __builtin_amdgcn_exp2f(x)
#else
#define EXP2(x) exp2f(x)
#endif
#if __has_builtin(__builtin_amdgcn_rcpf)
#define RCP(x) __builtin_amdgcn_rcpf(x)
#else
#define RCP(x) (1.0f / (x))
#endif

typedef const __attribute__((address_space(1))) void* as1_cvp;
typedef __attribute__((address_space(3))) void* as3_vp;

__device__ __forceinline__ void gload_lds16(const void* g, void* l) {
  // LDS dest is wave-uniform base + lane*16 (layouts below are linear in tid)
  __builtin_amdgcn_global_load_lds(
      (as1_cvp)(uintptr_t)g,
      (as3_vp)(unsigned int)(uintptr_t)l, 16, 0, 0);
}

// ---------- prep kernels ----------

__global__ __launch_bounds__(256) void k_cvt(const float* __restrict__ in,
                                             unsigned short* __restrict__ outp, int n) {
  int i = (blockIdx.x * 256 + threadIdx.x) * 4;
  if (i + 3 < n) {
    float4 v = *(const float4*)(in + i);
    union { unsigned short s[4]; uint2 u; } o;
    o.s[0] = f2b(v.x); o.s[1] = f2b(v.y); o.s[2] = f2b(v.z); o.s[3] = f2b(v.w);
    *(uint2*)(outp + i) = o.u;
  }
}

// in: R x C (f32, row-major) -> out: C x R (bf16)
__global__ __launch_bounds__(256) void k_tr(const float* __restrict__ in,
                                            unsigned short* __restrict__ out, int R, int C) {
  __shared__ unsigned short tile[64][65];
  const int tx = threadIdx.x & 63;
  const int ty = threadIdx.x >> 6;   // 0..3
  const int br = blockIdx.y * 64;
  const int bc = blockIdx.x * 64;
#pragma unroll
  for (int j = 0; j < 16; ++j) {
    int r = ty * 16 + j;
    tile[r][tx] = f2b(in[(size_t)(br + r) * C + bc + tx]);
  }
  __syncthreads();
#pragma unroll
  for (int j = 0; j < 16; ++j) {
    int r = ty * 16 + j;
    out[(size_t)(bc + r) * R + br + tx] = tile[tx][r];
  }
}

__global__ void k_trig(const int* __restrict__ pos, float* __restrict__ cs,
                       float* __restrict__ sn) {
  int t = blockIdx.x, i = threadIdx.x;  // block=64
  float p = (float)pos[t];
  float inv = EXP2(-(float)(2 * i) * (1.0f / 128.0f) * 13.287712379549449f);
  float f = p * inv;
  cs[t * 64 + i] = cosf(f);
  sn[t * 64 + i] = sinf(f);
}

// ---------- GEMM: A[M][K] bf16 row-major, Bt[N][K] bf16 (B transposed), C[M][N] f32 ----------

__global__ __launch_bounds__(256, 2) void k_gemm(const unsigned short* __restrict__ A,
                                                 const unsigned short* __restrict__ Bt,
                                                 float* __restrict__ C,
                                                 int M, int N, int K) {
  __shared__ unsigned short As[128 * 32];
  __shared__ unsigned short Bs[128 * 32];
  const int tid  = threadIdx.x;
  const int lane = tid & 63;
  const int wave = tid >> 6;

  // bijective XCD swizzle (grids are multiples of 8)
  const int nwgx = gridDim.x;
  const int nwg  = nwgx * gridDim.y;
  const int lin  = blockIdx.y * nwgx + blockIdx.x;
  const int cpx  = nwg >> 3;
  const int swz  = (lin & 7) * cpx + (lin >> 3);
  const int m0 = (swz / nwgx) * 128;
  const int n0 = (swz % nwgx) * 128;

  const int wr = (wave >> 1) * 64;
  const int wc = (wave & 1) * 64;
  const int lr  = lane & 15;
  const int lk  = (lane >> 4) * 8;
  const int li4 = (lane >> 4) * 4;

  f32x4 acc[4][4];
#pragma unroll
  for (int m = 0; m < 4; ++m)
#pragma unroll
    for (int n = 0; n < 4; ++n) acc[m][n] = (f32x4){0.f, 0.f, 0.f, 0.f};

  const int fl0 = tid * 8;
  const int r0 = fl0 >> 5, c0 = fl0 & 31;
  const int fl1 = (256 + tid) * 8;
  const int r1 = fl1 >> 5, c1 = fl1 & 31;
  const unsigned short* Ag0 = A  + (size_t)(m0 + r0) * K + c0;
  const unsigned short* Ag1 = A  + (size_t)(m0 + r1) * K + c1;
  const unsigned short* Bg0 = Bt + (size_t)(n0 + r0) * K + c0;
  const unsigned short* Bg1 = Bt + (size_t)(n0 + r1) * K + c1;

  for (int k0 = 0; k0 < K; k0 += 32) {
    gload_lds16(Ag0 + k0, &As[fl0]);
    gload_lds16(Ag1 + k0, &As[fl1]);
    gload_lds16(Bg0 + k0, &Bs[fl0]);
    gload_lds16(Bg1 + k0, &Bs[fl1]);
    __syncthreads();
    short8 af[4], bf[4];
#pragma unroll
    for (int m = 0; m < 4; ++m) af[m] = *(const short8*)&As[(wr + m * 16 + lr) * 32 + lk];
#pragma unroll
    for (int n = 0; n < 4; ++n) bf[n] = *(const short8*)&Bs[(wc + n * 16 + lr) * 32 + lk];
#pragma unroll
    for (int m = 0; m < 4; ++m)
#pragma unroll
      for (int n = 0; n < 4; ++n)
        acc[m][n] = __builtin_amdgcn_mfma_f32_16x16x32_bf16(af[m], bf[n], acc[m][n], 0, 0, 0);
    __syncthreads();
  }

#pragma unroll
  for (int m = 0; m < 4; ++m)
#pragma unroll
    for (int n = 0; n < 4; ++n)
#pragma unroll
      for (int i = 0; i < 4; ++i) {
        int row = m0 + wr + m * 16 + li4 + i;
        int col = n0 + wc + n * 16 + lr;
        C[(size_t)row * N + col] = acc[m][n][i];
      }
}

// ---------- RoPE + split: QKV f32 [T][8192] -> Q[h][t][d], K[h][t][d], Vt[h][d][t] (bf16) ----------

__global__ __launch_bounds__(256) void k_rope(const float* __restrict__ qkv,
                                              const float* __restrict__ cs,
                                              const float* __restrict__ sn,
                                              unsigned short* __restrict__ Q,
                                              unsigned short* __restrict__ K,
                                              unsigned short* __restrict__ Vt) {
  const int t = blockIdx.x;
  const int tid = threadIdx.x;
  const float* row = qkv + (size_t)t * QKVC;
  const float* c = cs + t * 64;
  const float* s = sn + t * 64;
  for (int p = tid; p < NHEADS * 64; p += 256) {
    int h = p >> 6, i = p & 63;
    float x1 = row[h * 128 + i], x2 = row[h * 128 + 64 + i];
    float cc = c[i], ss = s[i];
    size_t base = ((size_t)h * TSEQ + t) * HDIM;
    Q[base + i]      = f2b(x1 * cc - x2 * ss);
    Q[base + 64 + i] = f2b(x2 * cc + x1 * ss);
  }
  for (int p = tid; p < NKVH * 64; p += 256) {
    int h = p >> 6, i = p & 63;
    float x1 = row[DMODEL + h * 128 + i], x2 = row[DMODEL + h * 128 + 64 + i];
    float cc = c[i], ss = s[i];
    size_t base = ((size_t)h * TSEQ + t) * HDIM;
    K[base + i]      = f2b(x1 * cc - x2 * ss);
    K[base + 64 + i] = f2b(x2 * cc + x1 * ss);
  }
  for (int p = tid; p < NKVH * HDIM; p += 256) {
    int h = p >> 7, d = p & 127;
    Vt[((size_t)h * HDIM + d) * TSEQ + t] = f2b(row[DMODEL + NKVH * HDIM + h * 128 + d]);
  }
}

// ---------- attention v2 ----------
// Block = 4 waves, handles q-tile PAIR (j, 31-j) of 64 rows each -> exactly 33
// KV-steps of 64 per block (perfect balance). 768 blocks = 3/CU, all resident.
// K/V staged in LDS via global_load_lds w16 with XOR swizzle (pre-swizzled
// global source + swizzled ds_read, rule #21). blockIdx%8 = kv-group for XCD
// L2 affinity. P bounce per-wave, XOR-swizzled.
// P = softmax(cap*tanh(s/cap)) with static max = cap:
//   exp(l - 30) = 2^(-86.5617 * rcp(2^(s*0.09618)+1))

__global__ __launch_bounds__(256, 3) void k_attn2(const unsigned short* __restrict__ Q,
                                                  const unsigned short* __restrict__ K,
                                                  const unsigned short* __restrict__ V,  // Vt[h][d][t]
                                                  unsigned short* __restrict__ O) {
  __shared__ __align__(16) unsigned char KsB[16384];      // 64 s-rows x 256 B (swizzled)
  __shared__ __align__(16) unsigned char VsB[16384];      // 128 d-rows x 128 B (swizzled)
  __shared__ __align__(16) unsigned char PsB[4][2048];    // per-wave 16 q-rows x 128 B (swizzled)

  const int lin = blockIdx.x;
  const int g   = lin & 7;            // kv head == XCD hint
  const int rr  = lin >> 3;           // 0..95
  const int hg  = rr % 6;
  const int pr  = rr / 6;             // 0..15
  const int h   = g * 6 + hg;
  const int tid = threadIdx.x, wave = tid >> 6, lane = tid & 63;
  const int lr = lane & 15, lk = (lane >> 4) * 8, li4 = (lane >> 4) * 4;
  const unsigned short* Qh = Q + (size_t)h * (TSEQ * HDIM);
  const unsigned char*  Kb = (const unsigned char*)(K + (size_t)g * (TSEQ * HDIM));
  const unsigned char*  Vb = (const unsigned char*)(V + (size_t)g * (TSEQ * HDIM));
  unsigned char* Pw = PsB[wave];

  for (int half = 0; half < 2; ++half) {
    const int j  = half ? (31 - pr) : pr;     // q-tile index (64 rows)
    const int t0 = j * 64 + wave * 16;        // this wave's 16 rows
    const int nst = j + 1;

    short8 qf[4];
#pragma unroll
    for (int ks = 0; ks < 4; ++ks)
      qf[ks] = *(const short8*)(Qh + (size_t)(t0 + lr) * HDIM + ks * 32 + lk);

    f32x4 oacc[8];
#pragma unroll
    for (int n = 0; n < 8; ++n) oacc[n] = (f32x4){0.f, 0.f, 0.f, 0.f};
    float rs4[4] = {0.f, 0.f, 0.f, 0.f};

    for (int st = 0; st < nst; ++st) {
      const int s0 = st * 64;
      // ---- stage K tile (64x128 bf16) + V tile (128x64 bf16), swizzled source ----
#pragma unroll
      for (int c = 0; c < 4; ++c) {
        const int FF = tid * 16 + c * 4096;
        const int krow = FF >> 8;
        const int kcol = (FF & 255) ^ ((krow & 7) << 4);
        gload_lds16(Kb + (size_t)(s0 + krow) * 256 + kcol, KsB + FF);
        const int vrow = FF >> 7;
        const int vcol = (FF & 127) ^ ((vrow & 7) << 4);
        gload_lds16(Vb + (size_t)vrow * (TSEQ * 2) + (size_t)s0 * 2 + vcol, VsB + FF);
      }
      __syncthreads();   // compiler drains vmcnt(0) before barrier

      // ---- QK^T: 16 q-rows x 64 s-cols ----
      f32x4 sacc[4];
#pragma unroll
      for (int n = 0; n < 4; ++n) sacc[n] = (f32x4){0.f, 0.f, 0.f, 0.f};
#pragma unroll
      for (int ks = 0; ks < 4; ++ks) {
        short8 kf[4];
#pragma unroll
        for (int n = 0; n < 4; ++n) {
          const int row = n * 16 + lr;
          kf[n] = *(const short8*)(KsB + row * 256 + ((ks * 64 + lk * 2) ^ ((row & 7) << 4)));
        }
#pragma unroll
        for (int n = 0; n < 4; ++n)
          sacc[n] = __builtin_amdgcn_mfma_f32_16x16x32_bf16(qf[ks], kf[n], sacc[n], 0, 0, 0);
      }

      // ---- capped softmax (static max = cap), P -> LDS (swizzled) ----
      const bool lastst = (st == nst - 1);
#pragma unroll
      for (int n = 0; n < 4; ++n)
#pragma unroll
        for (int i = 0; i < 4; ++i) {
          float sv = sacc[n][i] * 0.08838834764831845f;   // 1/sqrt(128)
          float e = EXP2(sv * 0.09617966939259757f);       // e^(s/15)
          float p = EXP2(-86.5617024533378f * RCP(e + 1.0f));
          if (lastst && (s0 + n * 16 + lr > t0 + li4 + i)) p = 0.f;
          rs4[i] += p;
          const int prow = li4 + i;
          *(unsigned short*)(Pw + prow * 128 +
              (((n * 16 + lr) * 2) ^ ((prow & 7) << 4))) = f2b(p);
        }

      // ---- PV: oacc += P(16x64) * V(64x128) ----
#pragma unroll
      for (int ks2 = 0; ks2 < 2; ++ks2) {
        short8 pf = *(const short8*)(Pw + lr * 128 +
                         (((ks2 * 32 + lk) * 2) ^ ((lr & 7) << 4)));
        short8 vf[8];
#pragma unroll
        for (int n = 0; n < 8; ++n) {
          const int row = n * 16 + lr;
          vf[n] = *(const short8*)(VsB + row * 128 + ((ks2 * 64 + lk * 2) ^ ((row & 7) << 4)));
        }
#pragma unroll
        for (int n = 0; n < 8; ++n)
          oacc[n] = __builtin_amdgcn_mfma_f32_16x16x32_bf16(pf, vf[n], oacc[n], 0, 0, 0);
      }
      __syncthreads();   // protect LDS K/V before next stage
    }

    // ---- row-sum reduce over 16-lane col groups, normalize, store ----
    float inv4[4];
#pragma unroll
    for (int i = 0; i < 4; ++i) {
      float v = rs4[i];
      v += __shfl_xor(v, 1, 64);
      v += __shfl_xor(v, 2, 64);
      v += __shfl_xor(v, 4, 64);
      v += __shfl_xor(v, 8, 64);
      inv4[i] = RCP(v);
    }
#pragma unroll
    for (int n = 0; n < 8; ++n)
#pragma unroll
      for (int i = 0; i < 4; ++i)
        O[(size_t)(t0 + li4 + i) * DMODEL + h * HDIM + n * 16 + lr] =
            f2b(oacc[n][i] * inv4[i]);
  }
}

// ---------- launch ----------

extern "C" void kernel_launch(void* const* d_in, const int* in_sizes, int n_in,
                              void* d_out, int out_size, void* d_ws, size_t ws_size,
                              hipStream_t stream) {
  const int*   pos  = (const int*)d_in[0];
  const float* hid  = (const float*)d_in[1];
  const float* wqkv = (const float*)d_in[2];
  const float* wo   = (const float*)d_in[3];
  float* out = (float*)d_out;
  char* ws = (char*)d_ws;

  const size_t O_XB   = 0;                         // Xb bf16 [2048][6144]; later attn_out
  const size_t O_WQT  = 25165824;                  // Wqkv^T bf16 [8192][6144]; later Q/K/Vt
  const size_t O_WOT  = 125829120;                 // Wo^T bf16 [6144][6144]
  const size_t O_QKV  = 201326592;                 // QKV f32 [2048][8192]
  const size_t O_TRIG = 268435456;                 // cos/sin f32 [2048][64] each

  unsigned short* Xb  = (unsigned short*)(ws + O_XB);
  unsigned short* Wqt = (unsigned short*)(ws + O_WQT);
  unsigned short* Wot = (unsigned short*)(ws + O_WOT);
  float* QKV = (float*)(ws + O_QKV);
  float* CS  = (float*)(ws + O_TRIG);
  float* SN  = CS + TSEQ * 64;
  unsigned short* Qr = Wqt;                                  // [48][2048][128]
  unsigned short* Kr = Wqt + (size_t)NHEADS * TSEQ * HDIM;   // [8][2048][128]
  unsigned short* Vt = Kr + (size_t)NKVH * TSEQ * HDIM;      // [8][128][2048]
  unsigned short* AO = Xb;                                   // attn_out bf16 [2048][6144]

  k_cvt<<<(TSEQ * DMODEL) / (256 * 4), 256, 0, stream>>>(hid, Xb, TSEQ * DMODEL);
  k_tr<<<dim3(QKVC / 64, DMODEL / 64), 256, 0, stream>>>(wqkv, Wqt, DMODEL, QKVC);
  k_tr<<<dim3(DMODEL / 64, DMODEL / 64), 256, 0, stream>>>(wo, Wot, DMODEL, DMODEL);
  k_trig<<<TSEQ, 64, 0, stream>>>(pos, CS, SN);

  k_gemm<<<dim3(QKVC / 128, TSEQ / 128), 256, 0, stream>>>(Xb, Wqt, QKV, TSEQ, QKVC, DMODEL);
  k_rope<<<TSEQ, 256, 0, stream>>>(QKV, CS, SN, Qr, Kr, Vt);
  k_attn2<<<768, 256, 0, stream>>>(Qr, Kr, Vt, AO);
  k_gemm<<<dim3(DMODEL / 128, TSEQ / 128), 256, 0, stream>>>(AO, Wot, out, TSEQ, DMODEL, DMODEL);
}

// Round 3
// 571.506 us; speedup vs baseline: 1.8672x; 1.2977x over previous
//
#include <hip/hip_runtime.h>
#include <hip/hip_bf16.h>
#include <stdint.h>

#define TSEQ   2048
#define DMODEL 6144
#define NHEADS 48
#define NKVH   8
#define HDIM   128
#define QKVC   8192   // (48 + 2*8) * 128
#define GRP    6      // NHEADS / NKVH

typedef __attribute__((ext_vector_type(8))) short short8;
typedef __attribute__((ext_vector_type(4))) float f32x4;

// ---------- helpers ----------

__device__ __forceinline__ unsigned short f2b(float f) {
  union { float f; unsigned int u; } v; v.f = f;
  unsigned int u = v.u;
  unsigned int r = (u + 0x7FFFu + ((u >> 16) & 1u)) >> 16;  // RNE
  return (unsigned short)r;
}

#if __has_builtin(__builtin_amdgcn_exp2f)
#define EXP2(x) __builtin_amdgcn_exp2f(x)
#else
#define EXP2(x) exp2f(x)
#endif
#if __has_builtin(__builtin_amdgcn_rcpf)
#define RCP(x) __builtin_amdgcn_rcpf(x)
#else
#define RCP(x) (1.0f / (x))
#endif

typedef const __attribute__((address_space(1))) void* as1_cvp;
typedef __attribute__((address_space(3))) void* as3_vp;

__device__ __forceinline__ void gload_lds16(const void* g, void* l) {
  // LDS dest is wave-uniform base + lane*16 (layouts below are linear in tid)
  __builtin_amdgcn_global_load_lds(
      (as1_cvp)(uintptr_t)g,
      (as3_vp)(unsigned int)(uintptr_t)l, 16, 0, 0);
}

#define LGKM0 do { asm volatile("s_waitcnt lgkmcnt(0)" ::: "memory"); \
                   __builtin_amdgcn_sched_barrier(0); } while (0)
#define VMC(n) do { asm volatile("s_waitcnt vmcnt(" #n ")" ::: "memory"); \
                    __builtin_amdgcn_sched_barrier(0); } while (0)
#define BARR  do { asm volatile("s_barrier" ::: "memory"); } while (0)

// ---------- prep kernels ----------

__global__ __launch_bounds__(256) void k_cvt(const float* __restrict__ in,
                                             unsigned short* __restrict__ outp, int n) {
  int i = (blockIdx.x * 256 + threadIdx.x) * 4;
  if (i + 3 < n) {
    float4 v = *(const float4*)(in + i);
    union { unsigned short s[4]; uint2 u; } o;
    o.s[0] = f2b(v.x); o.s[1] = f2b(v.y); o.s[2] = f2b(v.z); o.s[3] = f2b(v.w);
    *(uint2*)(outp + i) = o.u;
  }
}

// in: R x C (f32, row-major) -> out: C x R (bf16)
__global__ __launch_bounds__(256) void k_tr(const float* __restrict__ in,
                                            unsigned short* __restrict__ out, int R, int C) {
  __shared__ unsigned short tile[64][65];
  const int tx = threadIdx.x & 63;
  const int ty = threadIdx.x >> 6;   // 0..3
  const int br = blockIdx.y * 64;
  const int bc = blockIdx.x * 64;
#pragma unroll
  for (int j = 0; j < 16; ++j) {
    int r = ty * 16 + j;
    tile[r][tx] = f2b(in[(size_t)(br + r) * C + bc + tx]);
  }
  __syncthreads();
#pragma unroll
  for (int j = 0; j < 16; ++j) {
    int r = ty * 16 + j;
    out[(size_t)(bc + r) * R + br + tx] = tile[tx][r];
  }
}

__global__ void k_trig(const int* __restrict__ pos, float* __restrict__ cs,
                       float* __restrict__ sn) {
  int t = blockIdx.x, i = threadIdx.x;  // block=64
  float p = (float)pos[t];
  float inv = EXP2(-(float)(2 * i) * (1.0f / 128.0f) * 13.287712379549449f);
  float f = p * inv;
  cs[t * 64 + i] = cosf(f);
  sn[t * 64 + i] = sinf(f);
}

// ---------- GEMM 256x256x64, 8-phase (T2+T3+T4+T5) ----------
// A[M][K] bf16 row-major, Bt[N][K] bf16, C[M][N] f32.
// 512 thr = 8 waves (2M x 4N); per-wave out 128x64 = acc[8][4] f32x4.
// LDS (dynamic 128 KiB): buf b at b*65536: A 256x64 (32KB, row stride 128B,
// XOR-swizzled byte^=(row&7)<<4), B at +32768 same.
// Per tile t (buf cur=t&1), 4 phases = C-quadrants (mh,nh):
//  ph1: read A-lo frags + B-lo frags; stage B(t+1)->buf cur^1; MFMA(0,0)
//  ph2: read B-hi; MFMA(0,1)
//  ph3: read A-hi + B-lo; MFMA(1,0)
//  ph4: read B-hi; stage A(t+2)->buf cur; MFMA(1,1); vmcnt(4); barrier
// Region safety: B(t+1) region last read tile t-1 ph4 (done: ph4-end barrier);
// A(cur) region last read tile t ph3 (done: ph3-end barrier).
// vmcnt(4): pending after wait = A(t+2) only; A(t+1),B(t+1) landed.

#define READ_A(mh) do { \
  _Pragma("unroll") for (int m = 0; m < 4; ++m) \
  _Pragma("unroll") for (int ks = 0; ks < 2; ++ks) \
    a[m][ks] = *(const short8*)(LA + (wm * 128 + (mh) * 64 + m * 16 + lr) * 128 \
                                + ((ks * 64 + lkb) ^ lsw)); } while (0)

#define READ_B(nh) do { \
  _Pragma("unroll") for (int n2 = 0; n2 < 2; ++n2) \
  _Pragma("unroll") for (int ks = 0; ks < 2; ++ks) \
    b[n2][ks] = *(const short8*)(LB + (wn * 64 + (nh) * 32 + n2 * 16 + lr) * 128 \
                                 + ((ks * 64 + lkb) ^ lsw)); } while (0)

#define CLUSTER(mh, nh) do { \
  __builtin_amdgcn_s_setprio(1); \
  _Pragma("unroll") for (int m = 0; m < 4; ++m) \
  _Pragma("unroll") for (int n2 = 0; n2 < 2; ++n2) \
  _Pragma("unroll") for (int ks = 0; ks < 2; ++ks) \
    acc[(mh) * 4 + m][(nh) * 2 + n2] = __builtin_amdgcn_mfma_f32_16x16x32_bf16( \
        a[m][ks], b[n2][ks], acc[(mh) * 4 + m][(nh) * 2 + n2], 0, 0, 0); \
  __builtin_amdgcn_s_setprio(0); } while (0)

#define STAGE_A(kt, bb) do { \
  _Pragma("unroll") for (int i = 0; i < 4; ++i) \
    gload_lds16(Asrc + (size_t)(kt) * 64 + (size_t)i * 64 * K, \
                lds + (bb) * 65536 + F + i * 8192); } while (0)

#define STAGE_B(kt, bb) do { \
  _Pragma("unroll") for (int i = 0; i < 4; ++i) \
    gload_lds16(Bsrc + (size_t)(kt) * 64 + (size_t)i * 64 * K, \
                lds + (bb) * 65536 + 32768 + F + i * 8192); } while (0)

__global__ __launch_bounds__(512, 2) void k_gemm8(const unsigned short* __restrict__ A,
                                                  const unsigned short* __restrict__ Bt,
                                                  float* __restrict__ C,
                                                  int M, int N, int K) {
  extern __shared__ __align__(16) unsigned char lds[];
  const int tid  = threadIdx.x;
  const int lane = tid & 63;
  const int wave = tid >> 6;
  const int wm = wave >> 2;           // 0..1
  const int wn = wave & 3;            // 0..3
  const int lr  = lane & 15;
  const int lkb = (lane >> 4) * 16;
  const int li4 = (lane >> 4) * 4;
  const int lsw = (lane & 7) << 4;    // read-side swizzle const

  // XCD n-stripe mapping: xcd = lin&7 owns n-cols [xcd*Cx, (xcd+1)*Cx)
  const int mt = M >> 8;
  const int nt = N >> 8;
  const int Cx = nt >> 3;
  const int lin = blockIdx.x;
  const int xcd = lin & 7;
  const int r   = lin >> 3;
  const int m0  = (r % mt) << 8;
  const int n0  = (xcd * Cx + r / mt) << 8;

  // staging: thread's 16B chunk; row advances 64 per load index
  const int F   = tid * 16;
  const int r0  = F >> 7;
  const int cbs = (F & 127) ^ ((r0 & 7) << 4);   // pre-swizzled source col
  const unsigned short* Asrc = A  + (size_t)(m0 + r0) * K + (cbs >> 1);
  const unsigned short* Bsrc = Bt + (size_t)(n0 + r0) * K + (cbs >> 1);

  const int NT = K >> 6;

  f32x4 acc[8][4];
#pragma unroll
  for (int i = 0; i < 8; ++i)
#pragma unroll
    for (int j = 0; j < 4; ++j) acc[i][j] = (f32x4){0.f, 0.f, 0.f, 0.f};

  // prologue: A(0),B(0)->buf0, A(1)->buf1; wait first 8, keep A(1) flying
  STAGE_A(0, 0);
  STAGE_B(0, 0);
  STAGE_A(1, 1);
  VMC(4);
  BARR;

  for (int t = 0; t < NT; ++t) {
    const int cur = t & 1;
    const unsigned char* LA = lds + cur * 65536;
    const unsigned char* LB = LA + 32768;
    short8 a[4][2], b[2][2];

    // ---- phase 1: quadrant (0,0)
    READ_A(0);
    READ_B(0);
    if (t + 1 < NT) STAGE_B(t + 1, cur ^ 1);
    LGKM0;
    CLUSTER(0, 0);
    BARR;

    // ---- phase 2: quadrant (0,1)
    READ_B(1);
    LGKM0;
    CLUSTER(0, 1);
    BARR;

    // ---- phase 3: quadrant (1,0)
    READ_A(1);
    READ_B(0);
    LGKM0;
    CLUSTER(1, 0);
    BARR;

    // ---- phase 4: quadrant (1,1)
    READ_B(1);
    if (t + 2 < NT) STAGE_A(t + 2, cur);
    LGKM0;
    CLUSTER(1, 1);
    if (t + 2 < NT) { VMC(4); } else { VMC(0); }
    BARR;
  }

#pragma unroll
  for (int mh = 0; mh < 2; ++mh)
#pragma unroll
    for (int m = 0; m < 4; ++m)
#pragma unroll
      for (int nh = 0; nh < 2; ++nh)
#pragma unroll
        for (int n2 = 0; n2 < 2; ++n2)
#pragma unroll
          for (int i = 0; i < 4; ++i) {
            int row = m0 + wm * 128 + mh * 64 + m * 16 + li4 + i;
            int col = n0 + wn * 64 + nh * 32 + n2 * 16 + lr;
            C[(size_t)row * N + col] = acc[mh * 4 + m][nh * 2 + n2][i];
          }
}

// ---------- RoPE + split: QKV f32 [T][8192] -> Q[h][t][d], K[h][t][d], Vt[h][d][t] (bf16) ----------

__global__ __launch_bounds__(256) void k_rope(const float* __restrict__ qkv,
                                              const float* __restrict__ cs,
                                              const float* __restrict__ sn,
                                              unsigned short* __restrict__ Q,
                                              unsigned short* __restrict__ K,
                                              unsigned short* __restrict__ Vt) {
  const int t = blockIdx.x;
  const int tid = threadIdx.x;
  const float* row = qkv + (size_t)t * QKVC;
  const float* c = cs + t * 64;
  const float* s = sn + t * 64;
  for (int p = tid; p < NHEADS * 64; p += 256) {
    int h = p >> 6, i = p & 63;
    float x1 = row[h * 128 + i], x2 = row[h * 128 + 64 + i];
    float cc = c[i], ss = s[i];
    size_t base = ((size_t)h * TSEQ + t) * HDIM;
    Q[base + i]      = f2b(x1 * cc - x2 * ss);
    Q[base + 64 + i] = f2b(x2 * cc + x1 * ss);
  }
  for (int p = tid; p < NKVH * 64; p += 256) {
    int h = p >> 6, i = p & 63;
    float x1 = row[DMODEL + h * 128 + i], x2 = row[DMODEL + h * 128 + 64 + i];
    float cc = c[i], ss = s[i];
    size_t base = ((size_t)h * TSEQ + t) * HDIM;
    K[base + i]      = f2b(x1 * cc - x2 * ss);
    K[base + 64 + i] = f2b(x2 * cc + x1 * ss);
  }
  for (int p = tid; p < NKVH * HDIM; p += 256) {
    int h = p >> 7, d = p & 127;
    Vt[((size_t)h * HDIM + d) * TSEQ + t] = f2b(row[DMODEL + NKVH * HDIM + h * 128 + d]);
  }
}

// ---------- attention (round-2 version, balanced pairs + LDS staging) ----------

__global__ __launch_bounds__(256, 3) void k_attn2(const unsigned short* __restrict__ Q,
                                                  const unsigned short* __restrict__ K,
                                                  const unsigned short* __restrict__ V,  // Vt[h][d][t]
                                                  unsigned short* __restrict__ O) {
  __shared__ __align__(16) unsigned char KsB[16384];      // 64 s-rows x 256 B (swizzled)
  __shared__ __align__(16) unsigned char VsB[16384];      // 128 d-rows x 128 B (swizzled)
  __shared__ __align__(16) unsigned char PsB[4][2048];    // per-wave 16 q-rows x 128 B (swizzled)

  const int lin = blockIdx.x;
  const int g   = lin & 7;            // kv head == XCD hint
  const int rr  = lin >> 3;           // 0..95
  const int hg  = rr % 6;
  const int pr  = rr / 6;             // 0..15
  const int h   = g * 6 + hg;
  const int tid = threadIdx.x, wave = tid >> 6, lane = tid & 63;
  const int lr = lane & 15, lk = (lane >> 4) * 8, li4 = (lane >> 4) * 4;
  const unsigned short* Qh = Q + (size_t)h * (TSEQ * HDIM);
  const unsigned char*  Kb = (const unsigned char*)(K + (size_t)g * (TSEQ * HDIM));
  const unsigned char*  Vb = (const unsigned char*)(V + (size_t)g * (TSEQ * HDIM));
  unsigned char* Pw = PsB[wave];

  for (int half = 0; half < 2; ++half) {
    const int j  = half ? (31 - pr) : pr;     // q-tile index (64 rows)
    const int t0 = j * 64 + wave * 16;        // this wave's 16 rows
    const int nst = j + 1;

    short8 qf[4];
#pragma unroll
    for (int ks = 0; ks < 4; ++ks)
      qf[ks] = *(const short8*)(Qh + (size_t)(t0 + lr) * HDIM + ks * 32 + lk);

    f32x4 oacc[8];
#pragma unroll
    for (int n = 0; n < 8; ++n) oacc[n] = (f32x4){0.f, 0.f, 0.f, 0.f};
    float rs4[4] = {0.f, 0.f, 0.f, 0.f};

    for (int st = 0; st < nst; ++st) {
      const int s0 = st * 64;
#pragma unroll
      for (int c = 0; c < 4; ++c) {
        const int FF = tid * 16 + c * 4096;
        const int krow = FF >> 8;
        const int kcol = (FF & 255) ^ ((krow & 7) << 4);
        gload_lds16(Kb + (size_t)(s0 + krow) * 256 + kcol, KsB + FF);
        const int vrow = FF >> 7;
        const int vcol = (FF & 127) ^ ((vrow & 7) << 4);
        gload_lds16(Vb + (size_t)vrow * (TSEQ * 2) + (size_t)s0 * 2 + vcol, VsB + FF);
      }
      __syncthreads();

      f32x4 sacc[4];
#pragma unroll
      for (int n = 0; n < 4; ++n) sacc[n] = (f32x4){0.f, 0.f, 0.f, 0.f};
#pragma unroll
      for (int ks = 0; ks < 4; ++ks) {
        short8 kf[4];
#pragma unroll
        for (int n = 0; n < 4; ++n) {
          const int row = n * 16 + lr;
          kf[n] = *(const short8*)(KsB + row * 256 + ((ks * 64 + lk * 2) ^ ((row & 7) << 4)));
        }
#pragma unroll
        for (int n = 0; n < 4; ++n)
          sacc[n] = __builtin_amdgcn_mfma_f32_16x16x32_bf16(qf[ks], kf[n], sacc[n], 0, 0, 0);
      }

      const bool lastst = (st == nst - 1);
#pragma unroll
      for (int n = 0; n < 4; ++n)
#pragma unroll
        for (int i = 0; i < 4; ++i) {
          float sv = sacc[n][i] * 0.08838834764831845f;   // 1/sqrt(128)
          float e = EXP2(sv * 0.09617966939259757f);       // e^(s/15)
          float p = EXP2(-86.5617024533378f * RCP(e + 1.0f));
          if (lastst && (s0 + n * 16 + lr > t0 + li4 + i)) p = 0.f;
          rs4[i] += p;
          const int prow = li4 + i;
          *(unsigned short*)(Pw + prow * 128 +
              (((n * 16 + lr) * 2) ^ ((prow & 7) << 4))) = f2b(p);
        }

#pragma unroll
      for (int ks2 = 0; ks2 < 2; ++ks2) {
        short8 pf = *(const short8*)(Pw + lr * 128 +
                         (((ks2 * 32 + lk) * 2) ^ ((lr & 7) << 4)));
        short8 vf[8];
#pragma unroll
        for (int n = 0; n < 8; ++n) {
          const int row = n * 16 + lr;
          vf[n] = *(const short8*)(VsB + row * 128 + ((ks2 * 64 + lk * 2) ^ ((row & 7) << 4)));
        }
#pragma unroll
        for (int n = 0; n < 8; ++n)
          oacc[n] = __builtin_amdgcn_mfma_f32_16x16x32_bf16(pf, vf[n], oacc[n], 0, 0, 0);
      }
      __syncthreads();
    }

    float inv4[4];
#pragma unroll
    for (int i = 0; i < 4; ++i) {
      float v = rs4[i];
      v += __shfl_xor(v, 1, 64);
      v += __shfl_xor(v, 2, 64);
      v += __shfl_xor(v, 4, 64);
      v += __shfl_xor(v, 8, 64);
      inv4[i] = RCP(v);
    }
#pragma unroll
    for (int n = 0; n < 8; ++n)
#pragma unroll
      for (int i = 0; i < 4; ++i)
        O[(size_t)(t0 + li4 + i) * DMODEL + h * HDIM + n * 16 + lr] =
            f2b(oacc[n][i] * inv4[i]);
  }
}

// ---------- launch ----------

extern "C" void kernel_launch(void* const* d_in, const int* in_sizes, int n_in,
                              void* d_out, int out_size, void* d_ws, size_t ws_size,
                              hipStream_t stream) {
  const int*   pos  = (const int*)d_in[0];
  const float* hid  = (const float*)d_in[1];
  const float* wqkv = (const float*)d_in[2];
  const float* wo   = (const float*)d_in[3];
  float* out = (float*)d_out;
  char* ws = (char*)d_ws;

  const size_t O_XB   = 0;                         // Xb bf16 [2048][6144]; later attn_out
  const size_t O_WQT  = 25165824;                  // Wqkv^T bf16 [8192][6144]; later Q/K/Vt
  const size_t O_WOT  = 125829120;                 // Wo^T bf16 [6144][6144]
  const size_t O_QKV  = 201326592;                 // QKV f32 [2048][8192]
  const size_t O_TRIG = 268435456;                 // cos/sin f32 [2048][64] each

  unsigned short* Xb  = (unsigned short*)(ws + O_XB);
  unsigned short* Wqt = (unsigned short*)(ws + O_WQT);
  unsigned short* Wot = (unsigned short*)(ws + O_WOT);
  float* QKV = (float*)(ws + O_QKV);
  float* CS  = (float*)(ws + O_TRIG);
  float* SN  = CS + TSEQ * 64;
  unsigned short* Qr = Wqt;                                  // [48][2048][128]
  unsigned short* Kr = Wqt + (size_t)NHEADS * TSEQ * HDIM;   // [8][2048][128]
  unsigned short* Vt = Kr + (size_t)NKVH * TSEQ * HDIM;      // [8][128][2048]
  unsigned short* AO = Xb;                                   // attn_out bf16 [2048][6144]

  hipFuncSetAttribute((const void*)k_gemm8,
                      hipFuncAttributeMaxDynamicSharedMemorySize, 131072);

  k_cvt<<<(TSEQ * DMODEL) / (256 * 4), 256, 0, stream>>>(hid, Xb, TSEQ * DMODEL);
  k_tr<<<dim3(QKVC / 64, DMODEL / 64), 256, 0, stream>>>(wqkv, Wqt, DMODEL, QKVC);
  k_tr<<<dim3(DMODEL / 64, DMODEL / 64), 256, 0, stream>>>(wo, Wot, DMODEL, DMODEL);
  k_trig<<<TSEQ, 64, 0, stream>>>(pos, CS, SN);

  k_gemm8<<<(TSEQ / 256) * (QKVC / 256), 512, 131072, stream>>>(Xb, Wqt, QKV,
                                                                TSEQ, QKVC, DMODEL);
  k_rope<<<TSEQ, 256, 0, stream>>>(QKV, CS, SN, Qr, Kr, Vt);
  k_attn2<<<768, 256, 0, stream>>>(Qr, Kr, Vt, AO);
  k_gemm8<<<(TSEQ / 256) * (DMODEL / 256), 512, 131072, stream>>>(AO, Wot, out,
                                                                  TSEQ, DMODEL, DMODEL);
}

// Round 4
// 554.738 us; speedup vs baseline: 1.9237x; 1.0302x over previous
//
#include <hip/hip_runtime.h>
#include <hip/hip_bf16.h>
#include <stdint.h>

#define TSEQ   2048
#define DMODEL 6144
#define NHEADS 48
#define NKVH   8
#define HDIM   128
#define QKVC   8192   // (48 + 2*8) * 128
#define GRP    6      // NHEADS / NKVH

typedef __attribute__((ext_vector_type(8))) short short8;
typedef __attribute__((ext_vector_type(4))) float f32x4;

// ---------- helpers ----------

__device__ __forceinline__ unsigned short f2b(float f) {
  union { float f; unsigned int u; } v; v.f = f;
  unsigned int u = v.u;
  unsigned int r = (u + 0x7FFFu + ((u >> 16) & 1u)) >> 16;  // RNE
  return (unsigned short)r;
}

#if __has_builtin(__builtin_amdgcn_exp2f)
#define EXP2(x) __builtin_amdgcn_exp2f(x)
#else
#define EXP2(x) exp2f(x)
#endif
#if __has_builtin(__builtin_amdgcn_rcpf)
#define RCP(x) __builtin_amdgcn_rcpf(x)
#else
#define RCP(x) (1.0f / (x))
#endif

typedef const __attribute__((address_space(1))) void* as1_cvp;
typedef __attribute__((address_space(3))) void* as3_vp;

__device__ __forceinline__ void gload_lds16(const void* g, void* l) {
  // LDS dest is wave-uniform base + lane*16 (layouts below are linear in tid)
  __builtin_amdgcn_global_load_lds(
      (as1_cvp)(uintptr_t)g,
      (as3_vp)(unsigned int)(uintptr_t)l, 16, 0, 0);
}

#define LGKM0 do { asm volatile("s_waitcnt lgkmcnt(0)" ::: "memory"); \
                   __builtin_amdgcn_sched_barrier(0); } while (0)
#define VMC(n) do { asm volatile("s_waitcnt vmcnt(" #n ")" ::: "memory"); \
                    __builtin_amdgcn_sched_barrier(0); } while (0)
#define BARR  do { asm volatile("s_barrier" ::: "memory"); } while (0)

// ---------- prep kernels ----------

__global__ __launch_bounds__(256) void k_cvt(const float* __restrict__ in,
                                             unsigned short* __restrict__ outp, int n) {
  int i = (blockIdx.x * 256 + threadIdx.x) * 8;
  if (i + 7 < n) {
    float4 va = *(const float4*)(in + i);
    float4 vb = *(const float4*)(in + i + 4);
    union { unsigned short s[8]; uint4 u; } o;
    o.s[0] = f2b(va.x); o.s[1] = f2b(va.y); o.s[2] = f2b(va.z); o.s[3] = f2b(va.w);
    o.s[4] = f2b(vb.x); o.s[5] = f2b(vb.y); o.s[6] = f2b(vb.z); o.s[7] = f2b(vb.w);
    *(uint4*)(outp + i) = o.u;
  }
}

// generic f32 -> bf16 64x64 tile transpose: out[c][r] = in[r][c]
// in rows stride istr, out rows stride ostr; blockIdx.z advances by zin/zout.
__global__ __launch_bounds__(256) void k_tr2(const float* __restrict__ in, long istr, long zin,
                                             unsigned short* __restrict__ out, long ostr, long zout) {
  __shared__ unsigned short tile[64][68];
  const int tid = threadIdx.x;
  const int br = blockIdx.y * 64;      // input row base
  const int bc = blockIdx.x * 64;      // input col base
  in  += (size_t)blockIdx.z * zin;
  out += (size_t)blockIdx.z * zout;
  const int row = tid >> 4;            // 0..15
  const int c4  = (tid & 15) * 4;
#pragma unroll
  for (int p = 0; p < 4; ++p) {
    const int r = p * 16 + row;
    float4 v = *(const float4*)(in + (size_t)(br + r) * istr + bc + c4);
    tile[r][c4 + 0] = f2b(v.x);
    tile[r][c4 + 1] = f2b(v.y);
    tile[r][c4 + 2] = f2b(v.z);
    tile[r][c4 + 3] = f2b(v.w);
  }
  __syncthreads();
#pragma unroll
  for (int p = 0; p < 4; ++p) {
    const int r = p * 16 + row;        // out row (= input col index)
    union { unsigned short s[4]; uint2 u; } o;
    o.s[0] = tile[c4 + 0][r];
    o.s[1] = tile[c4 + 1][r];
    o.s[2] = tile[c4 + 2][r];
    o.s[3] = tile[c4 + 3][r];
    *(uint2*)(out + (size_t)(bc + r) * ostr + br + c4) = o.u;
  }
}

__global__ void k_trig(const int* __restrict__ pos, float* __restrict__ cs,
                       float* __restrict__ sn) {
  int t = blockIdx.x, i = threadIdx.x;  // block=64
  float p = (float)pos[t];
  float inv = EXP2(-(float)(2 * i) * (1.0f / 128.0f) * 13.287712379549449f);
  float f = p * inv;
  cs[t * 64 + i] = cosf(f);
  sn[t * 64 + i] = sinf(f);
}

// ---------- GEMM 256x256x64, 8-phase (T2+T3+T4+T5), minimal LDS reads ----------
// A[M][K] bf16 row-major, Bt[N][K] bf16, C[M][N] f32.
// 512 thr = 8 waves (2M x 4N); per-wave out 128x64 = acc[8][4] f32x4.
// LDS (dynamic 128 KiB): buf b at b*65536: A 256 rows x 128 B (XOR-swizzled
// byte^=(row&7)<<4), B at +32768 same.
// Per tile t (buf cur=t&1), 4 phases; B frags b0/b1 held live (24 reads/tile):
//  ph1: read A-lo(8) + B-lo(4)->b0; stage B(t+1)->cur^1; MFMA(0,0)
//  ph2: read B-hi(4)->b1; MFMA(0,1)
//  ph3: read A-hi(8); MFMA(1,0) reuses b0
//  ph4: stage A(t+2)->cur; MFMA(1,1) reuses b1 (register-only); vmcnt(4); barr
// Region safety: B(t+1) last read in t-1 ph4-as-regs (b1 read in t-1 ph2; barrier
// chain ensures all ph2 reads done before t ph1 stage lands post-ph4-barrier);
// A(cur) last ds_read in ph3 (ph3-end barrier precedes ph4 stage).
// vmcnt(4) at ph4: pending = A(t+2) only; A(t+1), B(t+1) landed.

#define READ_A(mh) do { \
  _Pragma("unroll") for (int m = 0; m < 4; ++m) \
  _Pragma("unroll") for (int ks = 0; ks < 2; ++ks) \
    a[m][ks] = *(const short8*)(LA + (wm * 128 + (mh) * 64 + m * 16 + lr) * 128 \
                                + ((ks * 64 + lkb) ^ lsw)); } while (0)

#define READ_B(nh, bb) do { \
  _Pragma("unroll") for (int n2 = 0; n2 < 2; ++n2) \
  _Pragma("unroll") for (int ks = 0; ks < 2; ++ks) \
    bb[n2][ks] = *(const short8*)(LB + (wn * 64 + (nh) * 32 + n2 * 16 + lr) * 128 \
                                  + ((ks * 64 + lkb) ^ lsw)); } while (0)

#define CLUSTER(mh, nh, bb) do { \
  __builtin_amdgcn_s_setprio(1); \
  _Pragma("unroll") for (int m = 0; m < 4; ++m) \
  _Pragma("unroll") for (int n2 = 0; n2 < 2; ++n2) \
  _Pragma("unroll") for (int ks = 0; ks < 2; ++ks) \
    acc[(mh) * 4 + m][(nh) * 2 + n2] = __builtin_amdgcn_mfma_f32_16x16x32_bf16( \
        a[m][ks], bb[n2][ks], acc[(mh) * 4 + m][(nh) * 2 + n2], 0, 0, 0); \
  __builtin_amdgcn_s_setprio(0); } while (0)

#define STAGE_A(kt, bb) do { \
  _Pragma("unroll") for (int i = 0; i < 4; ++i) \
    gload_lds16(Asrc + (size_t)(kt) * 64 + (size_t)i * 64 * K, \
                lds + (bb) * 65536 + F + i * 8192); } while (0)

#define STAGE_B(kt, bb) do { \
  _Pragma("unroll") for (int i = 0; i < 4; ++i) \
    gload_lds16(Bsrc + (size_t)(kt) * 64 + (size_t)i * 64 * K, \
                lds + (bb) * 65536 + 32768 + F + i * 8192); } while (0)

__global__ __launch_bounds__(512, 2) void k_gemm8(const unsigned short* __restrict__ A,
                                                  const unsigned short* __restrict__ Bt,
                                                  float* __restrict__ C,
                                                  int M, int N, int K) {
  extern __shared__ __align__(16) unsigned char lds[];
  const int tid  = threadIdx.x;
  const int lane = tid & 63;
  const int wave = tid >> 6;
  const int wm = wave >> 2;           // 0..1
  const int wn = wave & 3;            // 0..3
  const int lr  = lane & 15;
  const int lkb = (lane >> 4) * 16;
  const int li4 = (lane >> 4) * 4;
  const int lsw = (lane & 7) << 4;    // read-side swizzle const

  // XCD n-stripe mapping: xcd = lin&7 owns n-cols [xcd*Cx, (xcd+1)*Cx)
  const int mt = M >> 8;
  const int nt = N >> 8;
  const int Cx = nt >> 3;
  const int lin = blockIdx.x;
  const int xcd = lin & 7;
  const int r   = lin >> 3;
  const int m0  = (r % mt) << 8;
  const int n0  = (xcd * Cx + r / mt) << 8;

  // staging: thread's 16B chunk; row advances 64 per load index
  const int F   = tid * 16;
  const int r0  = F >> 7;
  const int cbs = (F & 127) ^ ((r0 & 7) << 4);   // pre-swizzled source col
  const unsigned short* Asrc = A  + (size_t)(m0 + r0) * K + (cbs >> 1);
  const unsigned short* Bsrc = Bt + (size_t)(n0 + r0) * K + (cbs >> 1);

  const int NT = K >> 6;

  f32x4 acc[8][4];
#pragma unroll
  for (int i = 0; i < 8; ++i)
#pragma unroll
    for (int j = 0; j < 4; ++j) acc[i][j] = (f32x4){0.f, 0.f, 0.f, 0.f};

  // prologue: A(0),B(0)->buf0, A(1)->buf1; wait first 8, keep A(1) flying
  STAGE_A(0, 0);
  STAGE_B(0, 0);
  STAGE_A(1, 1);
  VMC(4);
  BARR;

  for (int t = 0; t < NT; ++t) {
    const int cur = t & 1;
    const unsigned char* LA = lds + cur * 65536;
    const unsigned char* LB = LA + 32768;
    short8 a[4][2], b0[2][2], b1[2][2];

    // ---- phase 1: quadrant (0,0)
    READ_A(0);
    READ_B(0, b0);
    if (t + 1 < NT) STAGE_B(t + 1, cur ^ 1);
    LGKM0;
    CLUSTER(0, 0, b0);
    BARR;

    // ---- phase 2: quadrant (0,1)
    READ_B(1, b1);
    LGKM0;
    CLUSTER(0, 1, b1);
    BARR;

    // ---- phase 3: quadrant (1,0) — reuses b0
    READ_A(1);
    LGKM0;
    CLUSTER(1, 0, b0);
    BARR;

    // ---- phase 4: quadrant (1,1) — register-only MFMA, overlaps stage
    if (t + 2 < NT) STAGE_A(t + 2, cur);
    CLUSTER(1, 1, b1);
    if (t + 2 < NT) { VMC(4); } else { VMC(0); }
    BARR;
  }

#pragma unroll
  for (int mh = 0; mh < 2; ++mh)
#pragma unroll
    for (int m = 0; m < 4; ++m)
#pragma unroll
      for (int nh = 0; nh < 2; ++nh)
#pragma unroll
        for (int n2 = 0; n2 < 2; ++n2)
#pragma unroll
          for (int i = 0; i < 4; ++i) {
            int row = m0 + wm * 128 + mh * 64 + m * 16 + li4 + i;
            int col = n0 + wn * 64 + nh * 32 + n2 * 16 + lr;
            C[(size_t)row * N + col] = acc[mh * 4 + m][nh * 2 + n2][i];
          }
}

// ---------- RoPE + split: QKV f32 [T][8192] -> Q[h][t][d], K[h][t][d] (bf16), vectorized ----------
// (V handled separately by k_tr2 into Vt[h][d][t])

__global__ __launch_bounds__(256) void k_rope(const float* __restrict__ qkv,
                                              const float* __restrict__ cs,
                                              const float* __restrict__ sn,
                                              unsigned short* __restrict__ Q,
                                              unsigned short* __restrict__ K) {
  const int t = blockIdx.x;
  const int tid = threadIdx.x;
  const float* row = qkv + (size_t)t * QKVC;
  const float* c = cs + t * 64;
  const float* s = sn + t * 64;
  // 56 heads (48 Q then 8 K, contiguous in qkv) x 16 quads of 4 pairs
  for (int p = tid; p < 56 * 16; p += 256) {
    const int h = p >> 4, q4 = (p & 15) * 4;
    const float* src = row + h * 128;
    float4 x1 = *(const float4*)(src + q4);
    float4 x2 = *(const float4*)(src + 64 + q4);
    float4 cc = *(const float4*)(c + q4);
    float4 ss = *(const float4*)(s + q4);
    unsigned short* dst = (h < NHEADS)
        ? Q + ((size_t)h * TSEQ + t) * HDIM
        : K + ((size_t)(h - NHEADS) * TSEQ + t) * HDIM;
    union { unsigned short sh[4]; uint2 u; } o1, o2;
    o1.sh[0] = f2b(x1.x * cc.x - x2.x * ss.x);
    o1.sh[1] = f2b(x1.y * cc.y - x2.y * ss.y);
    o1.sh[2] = f2b(x1.z * cc.z - x2.z * ss.z);
    o1.sh[3] = f2b(x1.w * cc.w - x2.w * ss.w);
    o2.sh[0] = f2b(x2.x * cc.x + x1.x * ss.x);
    o2.sh[1] = f2b(x2.y * cc.y + x1.y * ss.y);
    o2.sh[2] = f2b(x2.z * cc.z + x1.z * ss.z);
    o2.sh[3] = f2b(x2.w * cc.w + x1.w * ss.w);
    *(uint2*)(dst + q4) = o1.u;
    *(uint2*)(dst + 64 + q4) = o2.u;
  }
}

// ---------- attention (balanced pairs + LDS staging) ----------

__global__ __launch_bounds__(256, 3) void k_attn2(const unsigned short* __restrict__ Q,
                                                  const unsigned short* __restrict__ K,
                                                  const unsigned short* __restrict__ V,  // Vt[h][d][t]
                                                  unsigned short* __restrict__ O) {
  __shared__ __align__(16) unsigned char KsB[16384];      // 64 s-rows x 256 B (swizzled)
  __shared__ __align__(16) unsigned char VsB[16384];      // 128 d-rows x 128 B (swizzled)
  __shared__ __align__(16) unsigned char PsB[4][2048];    // per-wave 16 q-rows x 128 B (swizzled)

  const int lin = blockIdx.x;
  const int g   = lin & 7;            // kv head == XCD hint
  const int rr  = lin >> 3;           // 0..95
  const int hg  = rr % 6;
  const int pr  = rr / 6;             // 0..15
  const int h   = g * 6 + hg;
  const int tid = threadIdx.x, wave = tid >> 6, lane = tid & 63;
  const int lr = lane & 15, lk = (lane >> 4) * 8, li4 = (lane >> 4) * 4;
  const unsigned short* Qh = Q + (size_t)h * (TSEQ * HDIM);
  const unsigned char*  Kb = (const unsigned char*)(K + (size_t)g * (TSEQ * HDIM));
  const unsigned char*  Vb = (const unsigned char*)(V + (size_t)g * (TSEQ * HDIM));
  unsigned char* Pw = PsB[wave];

  for (int half = 0; half < 2; ++half) {
    const int j  = half ? (31 - pr) : pr;     // q-tile index (64 rows)
    const int t0 = j * 64 + wave * 16;        // this wave's 16 rows
    const int nst = j + 1;

    short8 qf[4];
#pragma unroll
    for (int ks = 0; ks < 4; ++ks)
      qf[ks] = *(const short8*)(Qh + (size_t)(t0 + lr) * HDIM + ks * 32 + lk);

    f32x4 oacc[8];
#pragma unroll
    for (int n = 0; n < 8; ++n) oacc[n] = (f32x4){0.f, 0.f, 0.f, 0.f};
    float rs4[4] = {0.f, 0.f, 0.f, 0.f};

    for (int st = 0; st < nst; ++st) {
      const int s0 = st * 64;
#pragma unroll
      for (int c = 0; c < 4; ++c) {
        const int FF = tid * 16 + c * 4096;
        const int krow = FF >> 8;
        const int kcol = (FF & 255) ^ ((krow & 7) << 4);
        gload_lds16(Kb + (size_t)(s0 + krow) * 256 + kcol, KsB + FF);
        const int vrow = FF >> 7;
        const int vcol = (FF & 127) ^ ((vrow & 7) << 4);
        gload_lds16(Vb + (size_t)vrow * (TSEQ * 2) + (size_t)s0 * 2 + vcol, VsB + FF);
      }
      __syncthreads();

      f32x4 sacc[4];
#pragma unroll
      for (int n = 0; n < 4; ++n) sacc[n] = (f32x4){0.f, 0.f, 0.f, 0.f};
#pragma unroll
      for (int ks = 0; ks < 4; ++ks) {
        short8 kf[4];
#pragma unroll
        for (int n = 0; n < 4; ++n) {
          const int row = n * 16 + lr;
          kf[n] = *(const short8*)(KsB + row * 256 + ((ks * 64 + lk * 2) ^ ((row & 7) << 4)));
        }
#pragma unroll
        for (int n = 0; n < 4; ++n)
          sacc[n] = __builtin_amdgcn_mfma_f32_16x16x32_bf16(qf[ks], kf[n], sacc[n], 0, 0, 0);
      }

      const bool lastst = (st == nst - 1);
#pragma unroll
      for (int n = 0; n < 4; ++n)
#pragma unroll
        for (int i = 0; i < 4; ++i) {
          float sv = sacc[n][i] * 0.08838834764831845f;   // 1/sqrt(128)
          float e = EXP2(sv * 0.09617966939259757f);       // e^(s/15)
          float p = EXP2(-86.5617024533378f * RCP(e + 1.0f));
          if (lastst && (s0 + n * 16 + lr > t0 + li4 + i)) p = 0.f;
          rs4[i] += p;
          const int prow = li4 + i;
          *(unsigned short*)(Pw + prow * 128 +
              (((n * 16 + lr) * 2) ^ ((prow & 7) << 4))) = f2b(p);
        }

#pragma unroll
      for (int ks2 = 0; ks2 < 2; ++ks2) {
        short8 pf = *(const short8*)(Pw + lr * 128 +
                         (((ks2 * 32 + lk) * 2) ^ ((lr & 7) << 4)));
        short8 vf[8];
#pragma unroll
        for (int n = 0; n < 8; ++n) {
          const int row = n * 16 + lr;
          vf[n] = *(const short8*)(VsB + row * 128 + ((ks2 * 64 + lk * 2) ^ ((row & 7) << 4)));
        }
#pragma unroll
        for (int n = 0; n < 8; ++n)
          oacc[n] = __builtin_amdgcn_mfma_f32_16x16x32_bf16(pf, vf[n], oacc[n], 0, 0, 0);
      }
      __syncthreads();
    }

    float inv4[4];
#pragma unroll
    for (int i = 0; i < 4; ++i) {
      float v = rs4[i];
      v += __shfl_xor(v, 1, 64);
      v += __shfl_xor(v, 2, 64);
      v += __shfl_xor(v, 4, 64);
      v += __shfl_xor(v, 8, 64);
      inv4[i] = RCP(v);
    }
#pragma unroll
    for (int n = 0; n < 8; ++n)
#pragma unroll
      for (int i = 0; i < 4; ++i)
        O[(size_t)(t0 + li4 + i) * DMODEL + h * HDIM + n * 16 + lr] =
            f2b(oacc[n][i] * inv4[i]);
  }
}

// ---------- launch ----------

extern "C" void kernel_launch(void* const* d_in, const int* in_sizes, int n_in,
                              void* d_out, int out_size, void* d_ws, size_t ws_size,
                              hipStream_t stream) {
  const int*   pos  = (const int*)d_in[0];
  const float* hid  = (const float*)d_in[1];
  const float* wqkv = (const float*)d_in[2];
  const float* wo   = (const float*)d_in[3];
  float* out = (float*)d_out;
  char* ws = (char*)d_ws;

  const size_t O_XB   = 0;                         // Xb bf16 [2048][6144]; later attn_out
  const size_t O_WQT  = 25165824;                  // Wqkv^T bf16 [8192][6144]; later Q/K/Vt
  const size_t O_WOT  = 125829120;                 // Wo^T bf16 [6144][6144]
  const size_t O_QKV  = 201326592;                 // QKV f32 [2048][8192]
  const size_t O_TRIG = 268435456;                 // cos/sin f32 [2048][64] each

  unsigned short* Xb  = (unsigned short*)(ws + O_XB);
  unsigned short* Wqt = (unsigned short*)(ws + O_WQT);
  unsigned short* Wot = (unsigned short*)(ws + O_WOT);
  float* QKV = (float*)(ws + O_QKV);
  float* CS  = (float*)(ws + O_TRIG);
  float* SN  = CS + TSEQ * 64;
  unsigned short* Qr = Wqt;                                  // [48][2048][128]
  unsigned short* Kr = Wqt + (size_t)NHEADS * TSEQ * HDIM;   // [8][2048][128]
  unsigned short* Vt = Kr + (size_t)NKVH * TSEQ * HDIM;      // [8][128][2048]
  unsigned short* AO = Xb;                                   // attn_out bf16 [2048][6144]

  hipFuncSetAttribute((const void*)k_gemm8,
                      hipFuncAttributeMaxDynamicSharedMemorySize, 131072);

  k_cvt<<<(TSEQ * DMODEL) / (256 * 8), 256, 0, stream>>>(hid, Xb, TSEQ * DMODEL);
  // Wqkv^T: in 6144x8192 -> out 8192x6144
  k_tr2<<<dim3(QKVC / 64, DMODEL / 64, 1), 256, 0, stream>>>(wqkv, QKVC, 0, Wqt, DMODEL, 0);
  // Wo^T: in 6144x6144 -> out 6144x6144
  k_tr2<<<dim3(DMODEL / 64, DMODEL / 64, 1), 256, 0, stream>>>(wo, DMODEL, 0, Wot, DMODEL, 0);
  k_trig<<<TSEQ, 64, 0, stream>>>(pos, CS, SN);

  k_gemm8<<<(TSEQ / 256) * (QKVC / 256), 512, 131072, stream>>>(Xb, Wqt, QKV,
                                                                TSEQ, QKVC, DMODEL);
  k_rope<<<TSEQ, 256, 0, stream>>>(QKV, CS, SN, Qr, Kr);
  // Vt: per head z, in QKV[t][7168 + z*128 + d] (2048x128) -> Vt[z][d][t]
  k_tr2<<<dim3(HDIM / 64, TSEQ / 64, NKVH), 256, 0, stream>>>(
      QKV + (size_t)(DMODEL + NKVH * HDIM), QKVC, HDIM,
      Vt, TSEQ, (size_t)HDIM * TSEQ);
  k_attn2<<<768, 256, 0, stream>>>(Qr, Kr, Vt, AO);
  k_gemm8<<<(TSEQ / 256) * (DMODEL / 256), 512, 131072, stream>>>(AO, Wot, out,
                                                                  TSEQ, DMODEL, DMODEL);
}

// Round 5
// 552.223 us; speedup vs baseline: 1.9324x; 1.0046x over previous
//
#include <hip/hip_runtime.h>
#include <hip/hip_bf16.h>
#include <stdint.h>

#define TSEQ   2048
#define DMODEL 6144
#define NHEADS 48
#define NKVH   8
#define HDIM   128
#define QKVC   8192   // (48 + 2*8) * 128
#define GRP    6      // NHEADS / NKVH

typedef __attribute__((ext_vector_type(8))) short short8;
typedef __attribute__((ext_vector_type(4))) float f32x4;

// ---------- helpers ----------

__device__ __forceinline__ unsigned short f2b(float f) {
  union { float f; unsigned int u; } v; v.f = f;
  unsigned int u = v.u;
  unsigned int r = (u + 0x7FFFu + ((u >> 16) & 1u)) >> 16;  // RNE
  return (unsigned short)r;
}

#if __has_builtin(__builtin_amdgcn_exp2f)
#define EXP2(x) __builtin_amdgcn_exp2f(x)
#else
#define EXP2(x) exp2f(x)
#endif
#if __has_builtin(__builtin_amdgcn_rcpf)
#define RCP(x) __builtin_amdgcn_rcpf(x)
#else
#define RCP(x) (1.0f / (x))
#endif

typedef const __attribute__((address_space(1))) void* as1_cvp;
typedef __attribute__((address_space(3))) void* as3_vp;

__device__ __forceinline__ void gload_lds16(const void* g, void* l) {
  // LDS dest is wave-uniform base + lane*16 (layouts below are linear in tid)
  __builtin_amdgcn_global_load_lds(
      (as1_cvp)(uintptr_t)g,
      (as3_vp)(unsigned int)(uintptr_t)l, 16, 0, 0);
}

#define LGKMC(n) do { asm volatile("s_waitcnt lgkmcnt(" #n ")" ::: "memory"); \
                      __builtin_amdgcn_sched_barrier(0); } while (0)
#define VMC(n) do { asm volatile("s_waitcnt vmcnt(" #n ")" ::: "memory"); \
                    __builtin_amdgcn_sched_barrier(0); } while (0)
#define BARR  do { asm volatile("s_barrier" ::: "memory"); } while (0)

// ---------- prep kernels ----------

__global__ __launch_bounds__(256) void k_cvt(const float* __restrict__ in,
                                             unsigned short* __restrict__ outp, int n) {
  int i = (blockIdx.x * 256 + threadIdx.x) * 8;
  if (i + 7 < n) {
    float4 va = *(const float4*)(in + i);
    float4 vb = *(const float4*)(in + i + 4);
    union { unsigned short s[8]; uint4 u; } o;
    o.s[0] = f2b(va.x); o.s[1] = f2b(va.y); o.s[2] = f2b(va.z); o.s[3] = f2b(va.w);
    o.s[4] = f2b(vb.x); o.s[5] = f2b(vb.y); o.s[6] = f2b(vb.z); o.s[7] = f2b(vb.w);
    *(uint4*)(outp + i) = o.u;
  }
}

// generic f32 -> bf16 64x64 tile transpose: out[c][r] = in[r][c]
__global__ __launch_bounds__(256) void k_tr2(const float* __restrict__ in, long istr, long zin,
                                             unsigned short* __restrict__ out, long ostr, long zout) {
  __shared__ unsigned short tile[64][68];
  const int tid = threadIdx.x;
  const int br = blockIdx.y * 64;      // input row base
  const int bc = blockIdx.x * 64;      // input col base
  in  += (size_t)blockIdx.z * zin;
  out += (size_t)blockIdx.z * zout;
  const int row = tid >> 4;            // 0..15
  const int c4  = (tid & 15) * 4;
#pragma unroll
  for (int p = 0; p < 4; ++p) {
    const int r = p * 16 + row;
    float4 v = *(const float4*)(in + (size_t)(br + r) * istr + bc + c4);
    tile[r][c4 + 0] = f2b(v.x);
    tile[r][c4 + 1] = f2b(v.y);
    tile[r][c4 + 2] = f2b(v.z);
    tile[r][c4 + 3] = f2b(v.w);
  }
  __syncthreads();
#pragma unroll
  for (int p = 0; p < 4; ++p) {
    const int r = p * 16 + row;        // out row (= input col index)
    union { unsigned short s[4]; uint2 u; } o;
    o.s[0] = tile[c4 + 0][r];
    o.s[1] = tile[c4 + 1][r];
    o.s[2] = tile[c4 + 2][r];
    o.s[3] = tile[c4 + 3][r];
    *(uint2*)(out + (size_t)(bc + r) * ostr + br + c4) = o.u;
  }
}

__global__ void k_trig(const int* __restrict__ pos, float* __restrict__ cs,
                       float* __restrict__ sn) {
  int t = blockIdx.x, i = threadIdx.x;  // block=64
  float p = (float)pos[t];
  float inv = EXP2(-(float)(2 * i) * (1.0f / 128.0f) * 13.287712379549449f);
  float f = p * inv;
  cs[t * 64 + i] = cosf(f);
  sn[t * 64 + i] = sinf(f);
}

// ---------- GEMM 256x256x64, pipelined counted-lgkm schedule ----------
// A[M][K] bf16 row-major, Bt[N][K] bf16, C[M][N] f32.
// 512 thr = 8 waves (2M x 4N); per-wave out 128x64 = acc[8][4] f32x4.
// LDS (dynamic 128 KiB): buf b at b*65536: A 256 rows x 128 B (XOR-swizzled
// byte^=(row&7)<<4), B at +32768 same.
// Per tile t (buf cur=t&1): issue ALL 24 ds_reads up-front (a0,b0 | b1 | a1),
// STAGE_B(t+1) interleaved; consume with counted lgkmcnt so read-issue
// overlaps MFMA across waves; 2 barriers/tile:
//   lgkm(12) MFMA(0,0); lgkm(8) MFMA(0,1); lgkm(0) MFMA(1,0);
//   BARR; STAGE_A(t+2,cur); MFMA(1,1); vmcnt(4); BARR
// Safety: lgkm(0) precedes mid-BARR in program order (asm+sched_barrier) so
// all waves' reads of buf cur are drained before STAGE_A writes land there.
// B(t+1) writes buf cur^1; its readers (tile t-1) drained >= 2 barriers ago.
// vmcnt(4) at tile end: leaves A(t+2) in flight; A(t+1), B(t+1) landed.

#define READ_A(mh, aa) do { \
  _Pragma("unroll") for (int m = 0; m < 4; ++m) \
  _Pragma("unroll") for (int ks = 0; ks < 2; ++ks) \
    aa[m][ks] = *(const short8*)(LA + (wm * 128 + (mh) * 64 + m * 16 + lr) * 128 \
                                 + ((ks * 64 + lkb) ^ lsw)); } while (0)

#define READ_B(nh, bb) do { \
  _Pragma("unroll") for (int n2 = 0; n2 < 2; ++n2) \
  _Pragma("unroll") for (int ks = 0; ks < 2; ++ks) \
    bb[n2][ks] = *(const short8*)(LB + (wn * 64 + (nh) * 32 + n2 * 16 + lr) * 128 \
                                  + ((ks * 64 + lkb) ^ lsw)); } while (0)

#define CLUSTER(mh, nh, aa, bb) do { \
  __builtin_amdgcn_s_setprio(1); \
  _Pragma("unroll") for (int m = 0; m < 4; ++m) \
  _Pragma("unroll") for (int n2 = 0; n2 < 2; ++n2) \
  _Pragma("unroll") for (int ks = 0; ks < 2; ++ks) \
    acc[(mh) * 4 + m][(nh) * 2 + n2] = __builtin_amdgcn_mfma_f32_16x16x32_bf16( \
        aa[m][ks], bb[n2][ks], acc[(mh) * 4 + m][(nh) * 2 + n2], 0, 0, 0); \
  __builtin_amdgcn_s_setprio(0); } while (0)

#define STAGE_A(kt, bb) do { \
  _Pragma("unroll") for (int i = 0; i < 4; ++i) \
    gload_lds16(Asrc + (size_t)(kt) * 64 + (size_t)i * 64 * K, \
                lds + (bb) * 65536 + F + i * 8192); } while (0)

#define STAGE_B(kt, bb) do { \
  _Pragma("unroll") for (int i = 0; i < 4; ++i) \
    gload_lds16(Bsrc + (size_t)(kt) * 64 + (size_t)i * 64 * K, \
                lds + (bb) * 65536 + 32768 + F + i * 8192); } while (0)

__global__ __launch_bounds__(512, 2) void k_gemm8(const unsigned short* __restrict__ A,
                                                  const unsigned short* __restrict__ Bt,
                                                  float* __restrict__ C,
                                                  int M, int N, int K) {
  extern __shared__ __align__(16) unsigned char lds[];
  const int tid  = threadIdx.x;
  const int lane = tid & 63;
  const int wave = tid >> 6;
  const int wm = wave >> 2;           // 0..1
  const int wn = wave & 3;            // 0..3
  const int lr  = lane & 15;
  const int lkb = (lane >> 4) * 16;
  const int li4 = (lane >> 4) * 4;
  const int lsw = (lane & 7) << 4;    // read-side swizzle const

  // XCD n-stripe mapping: xcd = lin&7 owns n-cols [xcd*Cx, (xcd+1)*Cx)
  const int mt = M >> 8;
  const int nt = N >> 8;
  const int Cx = nt >> 3;
  const int lin = blockIdx.x;
  const int xcd = lin & 7;
  const int r   = lin >> 3;
  const int m0  = (r % mt) << 8;
  const int n0  = (xcd * Cx + r / mt) << 8;

  // staging: thread's 16B chunk; row advances 64 per load index
  const int F   = tid * 16;
  const int r0  = F >> 7;
  const int cbs = (F & 127) ^ ((r0 & 7) << 4);   // pre-swizzled source col
  const unsigned short* Asrc = A  + (size_t)(m0 + r0) * K + (cbs >> 1);
  const unsigned short* Bsrc = Bt + (size_t)(n0 + r0) * K + (cbs >> 1);

  const int NT = K >> 6;

  f32x4 acc[8][4];
#pragma unroll
  for (int i = 0; i < 8; ++i)
#pragma unroll
    for (int j = 0; j < 4; ++j) acc[i][j] = (f32x4){0.f, 0.f, 0.f, 0.f};

  // prologue: A(0),B(0)->buf0, A(1)->buf1; wait first 8, keep A(1) flying
  STAGE_A(0, 0);
  STAGE_B(0, 0);
  STAGE_A(1, 1);
  VMC(4);
  BARR;

  for (int t = 0; t < NT; ++t) {
    const int cur = t & 1;
    const unsigned char* LA = lds + cur * 65536;
    const unsigned char* LB = LA + 32768;
    short8 a0[4][2], a1[4][2], b0[2][2], b1[2][2];

    // issue all reads up-front; stage B(t+1) interleaved
    READ_A(0, a0);                       // 8  (lgkm 8)
    READ_B(0, b0);                       // 4  (lgkm 12)
    if (t + 1 < NT) STAGE_B(t + 1, cur ^ 1);
    READ_B(1, b1);                       // 4  (lgkm 16)
    READ_A(1, a1);                       // 8  (lgkm 24)

    LGKMC(12);                           // a0,b0 landed
    CLUSTER(0, 0, a0, b0);
    LGKMC(8);                            // b1 landed
    CLUSTER(0, 1, a0, b1);
    LGKMC(0);                            // a1 landed (all reads drained)
    CLUSTER(1, 0, a1, b0);
    BARR;                                // all waves drained -> safe to overwrite A(cur)
    if (t + 2 < NT) STAGE_A(t + 2, cur);
    CLUSTER(1, 1, a1, b1);               // register-only, overlaps stage
    if (t + 2 < NT) { VMC(4); } else { VMC(0); }
    BARR;
  }

#pragma unroll
  for (int mh = 0; mh < 2; ++mh)
#pragma unroll
    for (int m = 0; m < 4; ++m)
#pragma unroll
      for (int nh = 0; nh < 2; ++nh)
#pragma unroll
        for (int n2 = 0; n2 < 2; ++n2)
#pragma unroll
          for (int i = 0; i < 4; ++i) {
            int row = m0 + wm * 128 + mh * 64 + m * 16 + li4 + i;
            int col = n0 + wn * 64 + nh * 32 + n2 * 16 + lr;
            C[(size_t)row * N + col] = acc[mh * 4 + m][nh * 2 + n2][i];
          }
}

// ---------- RoPE + split: QKV f32 [T][8192] -> Q[h][t][d], K[h][t][d] (bf16), vectorized ----------

__global__ __launch_bounds__(256) void k_rope(const float* __restrict__ qkv,
                                              const float* __restrict__ cs,
                                              const float* __restrict__ sn,
                                              unsigned short* __restrict__ Q,
                                              unsigned short* __restrict__ K) {
  const int t = blockIdx.x;
  const int tid = threadIdx.x;
  const float* row = qkv + (size_t)t * QKVC;
  const float* c = cs + t * 64;
  const float* s = sn + t * 64;
  for (int p = tid; p < 56 * 16; p += 256) {
    const int h = p >> 4, q4 = (p & 15) * 4;
    const float* src = row + h * 128;
    float4 x1 = *(const float4*)(src + q4);
    float4 x2 = *(const float4*)(src + 64 + q4);
    float4 cc = *(const float4*)(c + q4);
    float4 ss = *(const float4*)(s + q4);
    unsigned short* dst = (h < NHEADS)
        ? Q + ((size_t)h * TSEQ + t) * HDIM
        : K + ((size_t)(h - NHEADS) * TSEQ + t) * HDIM;
    union { unsigned short sh[4]; uint2 u; } o1, o2;
    o1.sh[0] = f2b(x1.x * cc.x - x2.x * ss.x);
    o1.sh[1] = f2b(x1.y * cc.y - x2.y * ss.y);
    o1.sh[2] = f2b(x1.z * cc.z - x2.z * ss.z);
    o1.sh[3] = f2b(x1.w * cc.w - x2.w * ss.w);
    o2.sh[0] = f2b(x2.x * cc.x + x1.x * ss.x);
    o2.sh[1] = f2b(x2.y * cc.y + x1.y * ss.y);
    o2.sh[2] = f2b(x2.z * cc.z + x1.z * ss.z);
    o2.sh[3] = f2b(x2.w * cc.w + x1.w * ss.w);
    *(uint2*)(dst + q4) = o1.u;
    *(uint2*)(dst + 64 + q4) = o2.u;
  }
}

// ---------- attention (balanced pairs + LDS staging) ----------

__global__ __launch_bounds__(256, 3) void k_attn2(const unsigned short* __restrict__ Q,
                                                  const unsigned short* __restrict__ K,
                                                  const unsigned short* __restrict__ V,  // Vt[h][d][t]
                                                  unsigned short* __restrict__ O) {
  __shared__ __align__(16) unsigned char KsB[16384];      // 64 s-rows x 256 B (swizzled)
  __shared__ __align__(16) unsigned char VsB[16384];      // 128 d-rows x 128 B (swizzled)
  __shared__ __align__(16) unsigned char PsB[4][2048];    // per-wave 16 q-rows x 128 B (swizzled)

  const int lin = blockIdx.x;
  const int g   = lin & 7;            // kv head == XCD hint
  const int rr  = lin >> 3;           // 0..95
  const int hg  = rr % 6;
  const int pr  = rr / 6;             // 0..15
  const int h   = g * 6 + hg;
  const int tid = threadIdx.x, wave = tid >> 6, lane = tid & 63;
  const int lr = lane & 15, lk = (lane >> 4) * 8, li4 = (lane >> 4) * 4;
  const unsigned short* Qh = Q + (size_t)h * (TSEQ * HDIM);
  const unsigned char*  Kb = (const unsigned char*)(K + (size_t)g * (TSEQ * HDIM));
  const unsigned char*  Vb = (const unsigned char*)(V + (size_t)g * (TSEQ * HDIM));
  unsigned char* Pw = PsB[wave];

  for (int half = 0; half < 2; ++half) {
    const int j  = half ? (31 - pr) : pr;     // q-tile index (64 rows)
    const int t0 = j * 64 + wave * 16;        // this wave's 16 rows
    const int nst = j + 1;

    short8 qf[4];
#pragma unroll
    for (int ks = 0; ks < 4; ++ks)
      qf[ks] = *(const short8*)(Qh + (size_t)(t0 + lr) * HDIM + ks * 32 + lk);

    f32x4 oacc[8];
#pragma unroll
    for (int n = 0; n < 8; ++n) oacc[n] = (f32x4){0.f, 0.f, 0.f, 0.f};
    float rs4[4] = {0.f, 0.f, 0.f, 0.f};

    for (int st = 0; st < nst; ++st) {
      const int s0 = st * 64;
#pragma unroll
      for (int c = 0; c < 4; ++c) {
        const int FF = tid * 16 + c * 4096;
        const int krow = FF >> 8;
        const int kcol = (FF & 255) ^ ((krow & 7) << 4);
        gload_lds16(Kb + (size_t)(s0 + krow) * 256 + kcol, KsB + FF);
        const int vrow = FF >> 7;
        const int vcol = (FF & 127) ^ ((vrow & 7) << 4);
        gload_lds16(Vb + (size_t)vrow * (TSEQ * 2) + (size_t)s0 * 2 + vcol, VsB + FF);
      }
      __syncthreads();

      f32x4 sacc[4];
#pragma unroll
      for (int n = 0; n < 4; ++n) sacc[n] = (f32x4){0.f, 0.f, 0.f, 0.f};
#pragma unroll
      for (int ks = 0; ks < 4; ++ks) {
        short8 kf[4];
#pragma unroll
        for (int n = 0; n < 4; ++n) {
          const int row = n * 16 + lr;
          kf[n] = *(const short8*)(KsB + row * 256 + ((ks * 64 + lk * 2) ^ ((row & 7) << 4)));
        }
#pragma unroll
        for (int n = 0; n < 4; ++n)
          sacc[n] = __builtin_amdgcn_mfma_f32_16x16x32_bf16(qf[ks], kf[n], sacc[n], 0, 0, 0);
      }

      const bool lastst = (st == nst - 1);
#pragma unroll
      for (int n = 0; n < 4; ++n)
#pragma unroll
        for (int i = 0; i < 4; ++i) {
          float sv = sacc[n][i] * 0.08838834764831845f;   // 1/sqrt(128)
          float e = EXP2(sv * 0.09617966939259757f);       // e^(s/15)
          float p = EXP2(-86.5617024533378f * RCP(e + 1.0f));
          if (lastst && (s0 + n * 16 + lr > t0 + li4 + i)) p = 0.f;
          rs4[i] += p;
          const int prow = li4 + i;
          *(unsigned short*)(Pw + prow * 128 +
              (((n * 16 + lr) * 2) ^ ((prow & 7) << 4))) = f2b(p);
        }

#pragma unroll
      for (int ks2 = 0; ks2 < 2; ++ks2) {
        short8 pf = *(const short8*)(Pw + lr * 128 +
                         (((ks2 * 32 + lk) * 2) ^ ((lr & 7) << 4)));
        short8 vf[8];
#pragma unroll
        for (int n = 0; n < 8; ++n) {
          const int row = n * 16 + lr;
          vf[n] = *(const short8*)(VsB + row * 128 + ((ks2 * 64 + lk * 2) ^ ((row & 7) << 4)));
        }
#pragma unroll
        for (int n = 0; n < 8; ++n)
          oacc[n] = __builtin_amdgcn_mfma_f32_16x16x32_bf16(pf, vf[n], oacc[n], 0, 0, 0);
      }
      __syncthreads();
    }

    float inv4[4];
#pragma unroll
    for (int i = 0; i < 4; ++i) {
      float v = rs4[i];
      v += __shfl_xor(v, 1, 64);
      v += __shfl_xor(v, 2, 64);
      v += __shfl_xor(v, 4, 64);
      v += __shfl_xor(v, 8, 64);
      inv4[i] = RCP(v);
    }
#pragma unroll
    for (int n = 0; n < 8; ++n)
#pragma unroll
      for (int i = 0; i < 4; ++i)
        O[(size_t)(t0 + li4 + i) * DMODEL + h * HDIM + n * 16 + lr] =
            f2b(oacc[n][i] * inv4[i]);
  }
}

// ---------- launch ----------

extern "C" void kernel_launch(void* const* d_in, const int* in_sizes, int n_in,
                              void* d_out, int out_size, void* d_ws, size_t ws_size,
                              hipStream_t stream) {
  const int*   pos  = (const int*)d_in[0];
  const float* hid  = (const float*)d_in[1];
  const float* wqkv = (const float*)d_in[2];
  const float* wo   = (const float*)d_in[3];
  float* out = (float*)d_out;
  char* ws = (char*)d_ws;

  const size_t O_XB   = 0;                         // Xb bf16 [2048][6144]; later attn_out
  const size_t O_WQT  = 25165824;                  // Wqkv^T bf16 [8192][6144]; later Q/K/Vt
  const size_t O_WOT  = 125829120;                 // Wo^T bf16 [6144][6144]
  const size_t O_QKV  = 201326592;                 // QKV f32 [2048][8192]
  const size_t O_TRIG = 268435456;                 // cos/sin f32 [2048][64] each

  unsigned short* Xb  = (unsigned short*)(ws + O_XB);
  unsigned short* Wqt = (unsigned short*)(ws + O_WQT);
  unsigned short* Wot = (unsigned short*)(ws + O_WOT);
  float* QKV = (float*)(ws + O_QKV);
  float* CS  = (float*)(ws + O_TRIG);
  float* SN  = CS + TSEQ * 64;
  unsigned short* Qr = Wqt;                                  // [48][2048][128]
  unsigned short* Kr = Wqt + (size_t)NHEADS * TSEQ * HDIM;   // [8][2048][128]
  unsigned short* Vt = Kr + (size_t)NKVH * TSEQ * HDIM;      // [8][128][2048]
  unsigned short* AO = Xb;                                   // attn_out bf16 [2048][6144]

  hipFuncSetAttribute((const void*)k_gemm8,
                      hipFuncAttributeMaxDynamicSharedMemorySize, 131072);

  k_cvt<<<(TSEQ * DMODEL) / (256 * 8), 256, 0, stream>>>(hid, Xb, TSEQ * DMODEL);
  // Wqkv^T: in 6144x8192 -> out 8192x6144
  k_tr2<<<dim3(QKVC / 64, DMODEL / 64, 1), 256, 0, stream>>>(wqkv, QKVC, 0, Wqt, DMODEL, 0);
  // Wo^T: in 6144x6144 -> out 6144x6144
  k_tr2<<<dim3(DMODEL / 64, DMODEL / 64, 1), 256, 0, stream>>>(wo, DMODEL, 0, Wot, DMODEL, 0);
  k_trig<<<TSEQ, 64, 0, stream>>>(pos, CS, SN);

  k_gemm8<<<(TSEQ / 256) * (QKVC / 256), 512, 131072, stream>>>(Xb, Wqt, QKV,
                                                                TSEQ, QKVC, DMODEL);
  k_rope<<<TSEQ, 256, 0, stream>>>(QKV, CS, SN, Qr, Kr);
  // Vt: per head z, in QKV[t][7168 + z*128 + d] (2048x128) -> Vt[z][d][t]
  k_tr2<<<dim3(HDIM / 64, TSEQ / 64, NKVH), 256, 0, stream>>>(
      QKV + (size_t)(DMODEL + NKVH * HDIM), QKVC, HDIM,
      Vt, TSEQ, (size_t)HDIM * TSEQ);
  k_attn2<<<768, 256, 0, stream>>>(Qr, Kr, Vt, AO);
  k_gemm8<<<(TSEQ / 256) * (DMODEL / 256), 512, 131072, stream>>>(AO, Wot, out,
                                                                  TSEQ, DMODEL, DMODEL);
}